// Round 3
// baseline (2131.413 us; speedup 1.0000x reference)
//
#include <hip/hip_runtime.h>
#include <hip/hip_bf16.h>
#include <math.h>

typedef __bf16 bf16;
typedef bf16 bf16x4 __attribute__((ext_vector_type(4)));
typedef bf16 bf16x8 __attribute__((ext_vector_type(8)));
typedef float f32x4 __attribute__((ext_vector_type(4)));

#define MFMA16(a, b, c) __builtin_amdgcn_mfma_f32_16x16x32_bf16((a), (b), (c), 0, 0, 0)

// q pre-scale: 1/sqrt(64) * log2(e), folded into QKV epilogue so attention
// can use raw v_exp_f32 (exp2) with no per-score multiply.
#define QSCALE 0.18033688011112042f

// async global->LDS, 16B per lane. LDS dest is wave-uniform base + lane*16
// (linear); global src is per-lane (carries the swizzle).
__device__ __forceinline__ void async16(const void* g, void* l) {
  __builtin_amdgcn_global_load_lds(
      (const __attribute__((address_space(1))) void*)g,
      (__attribute__((address_space(3))) void*)l, 16, 0, 0);
}

// ---------------- fp32 -> bf16 conversion ----------------
__global__ __launch_bounds__(256) void f2b_kernel(const float* __restrict__ in,
                                                  bf16* __restrict__ out, int n) {
  int i = (blockIdx.x * 256 + threadIdx.x) * 4;
  if (i >= n) return;
  f32x4 v = *(const f32x4*)(in + i);
  bf16x4 o = {(bf16)v[0], (bf16)v[1], (bf16)v[2], (bf16)v[3]};
  *(bf16x4*)(out + i) = o;
}

// ---------------- axial RoPE cos/sin table: [n=1024][d=32] ----------------
__global__ __launch_bounds__(256) void table_kernel(float* __restrict__ cosT,
                                                    float* __restrict__ sinT) {
  int idx = blockIdx.x * 256 + threadIdx.x;
  if (idx >= 1024 * 32) return;
  int n = idx >> 5, d = idx & 31;
  int hf = n >> 5, wf = n & 31;
  int bi = (d & 15) >> 1;
  float base = (1.0f + 73.0f * bi) * 3.14159265358979323846f;  // linspace(1,512,8)[i]*pi
  int p = (d < 16) ? hf : wf;
  float pos = (2.0f * (float)p - 31.0f) * (1.0f / 31.0f);      // linspace(-1,1,32)
  float f = pos * base;
  cosT[idx] = cosf(f);
  sinT[idx] = sinf(f);
}

// ---------------- 256x256 8-wave GEMM, 32-phase pipeline, 2 blocks/CU ----------
// Phase = one K-half (BK=32). LDS = 2-slot double buffer (16KB/slot/matrix,
// 64KB total -> 2 blocks/CU at VGPR<=128). Phase kh:
//   stage slot (kh+1)&1 (4 global_load_lds), s_waitcnt vmcnt(4) [counted: waits
//   only slot kh's 4 loads, next slot's 4 stay in flight], barrier, ds_read 12
//   frags + 32 MFMA, trailing barrier (WAR fence: next phase's stage overwrites
//   the slot just read).
// Lockstep-burst breaker: 2 independent blocks/CU overlap one block's MFMA
// burst with the other's read/stage burst (barrier groups are independent).
// Swizzle (64B rows): LDS (row,g16) holds global group g16^((row>>1)&3); read
// applies same XOR -> conflict-free b128 reads (pre-swizzled global source,
// linear LDS dest for global_load_lds).
// Block->XCD map: XCD j owns bm stripe [8j,8j+8), bn iterates fastest.
// EPI 0: QKV epilogue (RoPE on q,k; q pre-scaled; v transposed (b,h,d,n)), NBN=12
// EPI 1: proj epilogue (bias add, fp32 out), NBN=4
template <int EPI, int NBN>
__global__ __launch_bounds__(512, 4) void gemm_bt(
    const bf16* __restrict__ A, const bf16* __restrict__ W,
    bf16* __restrict__ oq, bf16* __restrict__ okk, bf16* __restrict__ ovt,
    const float* __restrict__ cosT, const float* __restrict__ sinT,
    float* __restrict__ outF, const float* __restrict__ bias) {
  constexpr int K = 1024;
  __shared__ bf16 As[2][256 * 32];
  __shared__ bf16 Bs[2][256 * 32];

  const int tid = threadIdx.x;
  const int lane = tid & 63;
  const int wid = tid >> 6;          // 0..7
  const int lo = lane & 15, hi = lane >> 4;
  const int wm = wid >> 2;           // 0..1 (M half)
  const int wn = wid & 3;            // 0..3 (N quarter)

  const int wg = blockIdx.x;
  const int xcd = wg & 7;
  const int i = wg >> 3;
  const int bm = xcd * 8 + i / NBN;
  const int bn = i % NBN;

  const bf16* Ab = A + (size_t)bm * 256 * K;
  const bf16* Wb = W + (size_t)bn * 256 * K;

  const f32x4 fzero = {0.f, 0.f, 0.f, 0.f};
  f32x4 acc[8][4];
#pragma unroll
  for (int i2 = 0; i2 < 8; ++i2)
#pragma unroll
    for (int j = 0; j < 4; ++j) acc[i2][j] = fzero;

  size_t srcOff[2];
  int ldsOff[2];
#pragma unroll
  for (int i2 = 0; i2 < 2; ++i2) {
    const int c = i2 * 512 + tid;
    const int row = c >> 2, g = c & 3;
    const int gsrc = g ^ ((row >> 1) & 3);
    srcOff[i2] = (size_t)row * K + gsrc * 8;
    ldsOff[i2] = c * 8;
  }

  auto stageSlot = [&](int slot, int kh) {
#pragma unroll
    for (int i2 = 0; i2 < 2; ++i2)
      async16(Ab + srcOff[i2] + kh * 32, &As[slot][ldsOff[i2]]);
#pragma unroll
    for (int i2 = 0; i2 < 2; ++i2)
      async16(Wb + srcOff[i2] + kh * 32, &Bs[slot][ldsOff[i2]]);
  };

  auto compute = [&](int slot) {
    bf16x8 af[8], bf[4];
#pragma unroll
    for (int mf = 0; mf < 8; ++mf) {
      const int row = wm * 128 + mf * 16 + lo;
      const int g = hi ^ ((row >> 1) & 3);
      af[mf] = *(const bf16x8*)&As[slot][row * 32 + g * 8];
    }
#pragma unroll
    for (int nf = 0; nf < 4; ++nf) {
      const int row = wn * 64 + nf * 16 + lo;
      const int g = hi ^ ((row >> 1) & 3);
      bf[nf] = *(const bf16x8*)&Bs[slot][row * 32 + g * 8];
    }
    __builtin_amdgcn_s_setprio(1);
#pragma unroll
    for (int mf = 0; mf < 8; ++mf)
#pragma unroll
      for (int nf = 0; nf < 4; ++nf)
        acc[mf][nf] = MFMA16(af[mf], bf[nf], acc[mf][nf]);
    __builtin_amdgcn_s_setprio(0);
  };

  // prologue: slot 0 in flight (4 loads)
  stageSlot(0, 0);

  // phases kh = 0..29 (15 x 2), slot = kh&1
  for (int kt = 0; kt < 15; ++kt) {
    stageSlot(1, 2 * kt + 1);
    asm volatile("s_waitcnt vmcnt(4)" ::: "memory");
    __builtin_amdgcn_s_barrier();
    compute(0);
    __builtin_amdgcn_s_barrier();
    stageSlot(0, 2 * kt + 2);
    asm volatile("s_waitcnt vmcnt(4)" ::: "memory");
    __builtin_amdgcn_s_barrier();
    compute(1);
    __builtin_amdgcn_s_barrier();
  }
  // kh = 30
  stageSlot(1, 31);
  asm volatile("s_waitcnt vmcnt(4)" ::: "memory");
  __builtin_amdgcn_s_barrier();
  compute(0);
  __builtin_amdgcn_s_barrier();
  // kh = 31
  asm volatile("s_waitcnt vmcnt(0)" ::: "memory");
  __builtin_amdgcn_s_barrier();
  compute(1);

  const int rb0 = bm * 256 + wm * 128;
  const int jb0 = bn * 256 + wn * 64;

  if constexpr (EPI == 0) {
#pragma unroll
    for (int ac = 0; ac < 4; ++ac) {
      const int j = jb0 + ac * 16 + lo;
      const int which = j >> 10;        // 0=q 1=k 2=v (uniform per wave)
      const int f = j & 1023;
      const int h = f >> 6, d = f & 63; // d = ac*16+lo; d<32 <=> ac<2
#pragma unroll
      for (int ar = 0; ar < 8; ++ar) {
        const int rb = rb0 + ar * 16 + 4 * hi;
        f32x4 v = acc[ar][ac];
        if (which == 2) {
          const int b = rb >> 10, n0 = rb & 1023;
          bf16x4 pk = {(bf16)v[0], (bf16)v[1], (bf16)v[2], (bf16)v[3]};
          *(bf16x4*)(ovt + ((size_t)((b * 16 + h) * 64 + d)) * 1024 + n0) = pk;
        } else {
          bf16* dst = which ? okk : oq;
          const float sc = which ? 1.0f : QSCALE;
#pragma unroll
          for (int reg = 0; reg < 4; ++reg) {
            const int r = rb + reg;
            const int b = r >> 10, n = r & 1023;
            float val = v[reg];
            float res;
            if (d < 32) {
              float c = cosT[n * 32 + d];
              float s = sinT[n * 32 + d];
              float pp = __shfl_xor(val, 1);  // rotary partner: adjacent lane = d^1
              res = (d & 1) ? fmaf(val, c, pp * s) : fmaf(val, c, -(pp * s));
            } else {
              res = val;
            }
            dst[((size_t)((b * 16 + h) * 1024 + n)) * 64 + d] = (bf16)(res * sc);
          }
        }
      }
    }
  } else {
#pragma unroll
    for (int ac = 0; ac < 4; ++ac) {
      const int j = jb0 + ac * 16 + lo;
      const float bv = bias[j];
#pragma unroll
      for (int ar = 0; ar < 8; ++ar) {
        const int rb = rb0 + ar * 16 + 4 * hi;
#pragma unroll
        for (int reg = 0; reg < 4; ++reg)
          outF[(size_t)(rb + reg) * 1024 + j] = acc[ar][ac][reg] + bv;
      }
    }
  }
}

// ---------------- flash attention: 8 waves x 32 q-rows (256 rows/block) -------
// (unchanged from previous round — see comments there)
__global__ __launch_bounds__(512, 4) void attn_fwd(const bf16* __restrict__ q,
                                                   const bf16* __restrict__ k,
                                                   const bf16* __restrict__ vt,
                                                   bf16* __restrict__ o) {
  __shared__ bf16 Kt[2][64 * 64];
  __shared__ bf16 Vt[2][64 * 64];
  __shared__ bf16 Pt[8][32 * 68];
  const int tid = threadIdx.x;
  const int lane = tid & 63, wid = tid >> 6;
  const int lo = lane & 15, hi = lane >> 4;
  const int j = blockIdx.x;                  // 0..1023
  const int bh = (j & 7) + ((j >> 5) << 3);  // 0..255
  const int qt = (j >> 3) & 3;               // 0..3
  const bf16* qg = q + (size_t)bh * 65536;
  const bf16* kg = k + (size_t)bh * 65536;
  const bf16* vg = vt + (size_t)bh * 65536;

  bf16x8 qf[2][2];
#pragma unroll
  for (int rg = 0; rg < 2; ++rg) {
    const int qrow = qt * 256 + wid * 32 + rg * 16 + lo;
#pragma unroll
    for (int ch = 0; ch < 2; ++ch)
      qf[rg][ch] = *(const bf16x8*)(qg + (size_t)qrow * 64 + ch * 32 + 8 * hi);
  }

  const int srow = tid >> 3;
  const int sgsrc = (tid & 7) ^ (srow & 7);
  auto stageKV = [&](int buf, int kv) {
    async16(kg + (size_t)(kv * 64 + srow) * 64 + sgsrc * 8, &Kt[buf][tid * 8]);
    async16(vg + (size_t)srow * 1024 + kv * 64 + sgsrc * 8, &Vt[buf][tid * 8]);
  };

  asm volatile("s_waitcnt vmcnt(0)" ::: "memory");
  stageKV(0, 0);

  const f32x4 fzero = {0.f, 0.f, 0.f, 0.f};
  f32x4 of[2][4];
  float psum[2][4];
#pragma unroll
  for (int rg = 0; rg < 2; ++rg)
#pragma unroll
    for (int r = 0; r < 4; ++r) {
      of[rg][r] = fzero;
      psum[rg][r] = 0.f;
    }

  const int m7 = lo & 7;

  for (int kv = 0; kv < 16; ++kv) {
    const int cur = kv & 1;
    if (kv < 15) {
      stageKV(cur ^ 1, kv + 1);
      asm volatile("s_waitcnt vmcnt(2)" ::: "memory");
    } else {
      asm volatile("s_waitcnt vmcnt(0)" ::: "memory");
    }
    __builtin_amdgcn_s_barrier();

#pragma unroll
    for (int kf = 0; kf < 4; ++kf) {
      const int r = kf * 16 + lo;
      bf16x8 kb0 = *(const bf16x8*)&Kt[cur][r * 64 + ((hi ^ m7) * 8)];
      bf16x8 kb1 = *(const bf16x8*)&Kt[cur][r * 64 + (((hi + 4) ^ m7) * 8)];
#pragma unroll
      for (int rg = 0; rg < 2; ++rg) {
        f32x4 z = fzero;
        z = MFMA16(qf[rg][0], kb0, z);
        z = MFMA16(qf[rg][1], kb1, z);
#pragma unroll
        for (int reg = 0; reg < 4; ++reg) {
          float p = __builtin_amdgcn_exp2f(z[reg]);
          psum[rg][reg] += p;
          Pt[wid][(rg * 16 + 4 * hi + reg) * 68 + kf * 16 + lo] = (bf16)p;
        }
      }
    }

    bf16x8 pa[2][2];
#pragma unroll
    for (int rg = 0; rg < 2; ++rg)
#pragma unroll
      for (int ch = 0; ch < 2; ++ch)
        pa[rg][ch] = *(const bf16x8*)&Pt[wid][(rg * 16 + lo) * 68 + ch * 32 + 8 * hi];
#pragma unroll
    for (int df = 0; df < 4; ++df) {
      const int r = df * 16 + lo;
      bf16x8 vb0 = *(const bf16x8*)&Vt[cur][r * 64 + ((hi ^ m7) * 8)];
      bf16x8 vb1 = *(const bf16x8*)&Vt[cur][r * 64 + (((hi + 4) ^ m7) * 8)];
#pragma unroll
      for (int rg = 0; rg < 2; ++rg) {
        of[rg][df] = MFMA16(pa[rg][0], vb0, of[rg][df]);
        of[rg][df] = MFMA16(pa[rg][1], vb1, of[rg][df]);
      }
    }
    __syncthreads();
  }

#pragma unroll
  for (int off = 1; off < 16; off <<= 1) {
#pragma unroll
    for (int rg = 0; rg < 2; ++rg)
#pragma unroll
      for (int reg = 0; reg < 4; ++reg) psum[rg][reg] += __shfl_xor(psum[rg][reg], off);
  }

  const int b = bh >> 4, h = bh & 15;
#pragma unroll
  for (int rg = 0; rg < 2; ++rg)
#pragma unroll
    for (int reg = 0; reg < 4; ++reg) {
      const int n = qt * 256 + wid * 32 + rg * 16 + 4 * hi + reg;
      const float inv = 1.0f / psum[rg][reg];
#pragma unroll
      for (int df = 0; df < 4; ++df)
        o[((size_t)(b * 1024 + n)) * 1024 + h * 64 + df * 16 + lo] =
            (bf16)(of[rg][df][reg] * inv);
    }
}

extern "C" void kernel_launch(void* const* d_in, const int* in_sizes, int n_in,
                              void* d_out, int out_size, void* d_ws, size_t ws_size,
                              hipStream_t stream) {
  (void)in_sizes; (void)n_in; (void)out_size; (void)ws_size;
  const float* x = (const float*)d_in[0];
  const float* wqkv = (const float*)d_in[1];
  const float* wproj = (const float*)d_in[2];
  const float* bproj = (const float*)d_in[3];

  char* ws = (char*)d_ws;
  bf16* xb = (bf16*)(ws);                  // 33554432 B (x bf16; reused as attnout)
  bf16* wqb = (bf16*)(ws + 33554432);      // 6291456 B
  bf16* wpb = (bf16*)(ws + 39845888);      // 2097152 B
  float* cosT = (float*)(ws + 41943040);   // 131072 B
  float* sinT = (float*)(ws + 42074112);   // 131072 B
  bf16* qb = (bf16*)(ws + 42205184);       // 33554432 B  (b,h,n,d), pre-scaled
  bf16* kb = (bf16*)(ws + 75759616);       // 33554432 B  (b,h,n,d)
  bf16* vtb = (bf16*)(ws + 109314048);     // 33554432 B  (b,h,d,n)
  // total ws use: 142868480 B

  f2b_kernel<<<16384, 256, 0, stream>>>(x, xb, 16 * 1024 * 1024);
  f2b_kernel<<<3072, 256, 0, stream>>>(wqkv, wqb, 3 * 1024 * 1024);
  f2b_kernel<<<1024, 256, 0, stream>>>(wproj, wpb, 1024 * 1024);
  table_kernel<<<128, 256, 0, stream>>>(cosT, sinT);

  // QKV: M=16384, N=3072, K=1024 -> 64 bm x 12 bn = 768 blocks of 256x256
  gemm_bt<0, 12><<<768, 512, 0, stream>>>(xb, wqb, qb, kb, vtb, cosT, sinT,
                                          nullptr, nullptr);
  // attention: 1024 blocks (4 q-tiles x 256 heads, XCD-chunked), 8 waves each
  attn_fwd<<<1024, 512, 0, stream>>>(qb, kb, vtb, xb);
  // proj: M=16384, N=1024, K=1024 -> 64 bm x 4 bn = 256 blocks
  gemm_bt<1, 4><<<256, 512, 0, stream>>>(xb, wpb, nullptr, nullptr, nullptr,
                                         nullptr, nullptr, (float*)d_out, bproj);
}

// Round 4
// 278.743 us; speedup vs baseline: 7.6465x; 7.6465x over previous
//
#include <hip/hip_runtime.h>
#include <hip/hip_bf16.h>
#include <math.h>

typedef __bf16 bf16;
typedef bf16 bf16x4 __attribute__((ext_vector_type(4)));
typedef bf16 bf16x8 __attribute__((ext_vector_type(8)));
typedef float f32x4 __attribute__((ext_vector_type(4)));

#define MFMA16(a, b, c) __builtin_amdgcn_mfma_f32_16x16x32_bf16((a), (b), (c), 0, 0, 0)

// q pre-scale: 1/sqrt(64) * log2(e), folded into QKV epilogue so attention
// can use raw v_exp_f32 (exp2) with no per-score multiply.
#define QSCALE 0.18033688011112042f

// async global->LDS, 16B per lane. LDS dest is wave-uniform base + lane*16
// (linear); global src is per-lane (carries the swizzle).
__device__ __forceinline__ void async16(const void* g, void* l) {
  __builtin_amdgcn_global_load_lds(
      (const __attribute__((address_space(1))) void*)g,
      (__attribute__((address_space(3))) void*)l, 16, 0, 0);
}

// ---------------- fp32 -> bf16 conversion ----------------
__global__ __launch_bounds__(256) void f2b_kernel(const float* __restrict__ in,
                                                  bf16* __restrict__ out, int n) {
  int i = (blockIdx.x * 256 + threadIdx.x) * 4;
  if (i >= n) return;
  f32x4 v = *(const f32x4*)(in + i);
  bf16x4 o = {(bf16)v[0], (bf16)v[1], (bf16)v[2], (bf16)v[3]};
  *(bf16x4*)(out + i) = o;
}

// ---------------- axial RoPE cos/sin table: [n=1024][d=32] ----------------
__global__ __launch_bounds__(256) void table_kernel(float* __restrict__ cosT,
                                                    float* __restrict__ sinT) {
  int idx = blockIdx.x * 256 + threadIdx.x;
  if (idx >= 1024 * 32) return;
  int n = idx >> 5, d = idx & 31;
  int hf = n >> 5, wf = n & 31;
  int bi = (d & 15) >> 1;
  float base = (1.0f + 73.0f * bi) * 3.14159265358979323846f;  // linspace(1,512,8)[i]*pi
  int p = (d < 16) ? hf : wf;
  float pos = (2.0f * (float)p - 31.0f) * (1.0f / 31.0f);      // linspace(-1,1,32)
  float f = pos * base;
  cosT[idx] = cosf(f);
  sinT[idx] = sinf(f);
}

// ---------------- 256x256 8-wave GEMM, 32-phase counted-vmcnt pipeline ----------
// A: MxK row-major, W: NxK row-major. Phase = one K-half (BK=32). LDS is a
// 4-slot ring per matrix (slot kh -> kh&3, 16KB each, 128KB total). Phase kh:
//   issue stage of slot kh+2 (4 global_load_lds), s_waitcnt vmcnt(8)  [counted:
//   forces only slot kh's 4 oldest loads; 8 stay in flight across the barrier],
//   barrier, ds_read 12 frags, 32 MFMA (setprio-wrapped).
// Race-freedom: slot (kh+2)&3's tenant kh-2 was fully read (its MFMA precedes
// barrier(kh-1)) before any wave issues the stage at phase kh. One barrier per
// phase; vmcnt hits 0 only at the last phase.
// REGISTER NOTE: must stay at __launch_bounds__(512,2) — acc[8][4] lives as 128
// AGPRs + ~112 VGPRs = 240/256. (512,4) halves the budget and spills acc to
// scratch (round-3 post-mortem: 2.4GB scratch FETCH, 12x slowdown).
// Swizzle (64B rows): LDS (row, g16) holds global group g16^((row>>1)&3); read
// applies same XOR (pre-swizzled global source, linear LDS dest).
// Block map: XCD j owns bm stripe [8j,8j+8); within the stripe, blocks are
// ordered in 4bm x 4bn squares so the ~32 concurrent blocks per XCD touch
// ~4 A-panels + 4 B-panels (~4MB) instead of 3A + NBN B (7.5MB > 4MB L2).
// EPI 0: QKV epilogue (RoPE on q,k; q pre-scaled; v transposed (b,h,d,n)), NBN=12
// EPI 1: proj epilogue (bias add, fp32 out), NBN=4
template <int EPI, int NBN>
__global__ __launch_bounds__(512, 2) void gemm_bt(
    const bf16* __restrict__ A, const bf16* __restrict__ W,
    bf16* __restrict__ oq, bf16* __restrict__ okk, bf16* __restrict__ ovt,
    const float* __restrict__ cosT, const float* __restrict__ sinT,
    float* __restrict__ outF, const float* __restrict__ bias) {
  constexpr int K = 1024;
  __shared__ bf16 As[4][256 * 32];
  __shared__ bf16 Bs[4][256 * 32];

  const int tid = threadIdx.x;
  const int lane = tid & 63;
  const int wid = tid >> 6;          // 0..7
  const int lo = lane & 15, hi = lane >> 4;
  const int wm = wid >> 2;           // 0..1 (M half)
  const int wn = wid & 3;            // 0..3 (N quarter)

  // XCD-stripe block mapping with 4x4 square ordering inside the stripe.
  const int wg = blockIdx.x;
  const int xcd = wg & 7;
  const int i = wg >> 3;             // 0 .. 8*NBN-1
  const int s = i >> 4;              // square index: (s&1)=bm half, (s>>1)=bn quad
  const int r = i & 15;
  const int bm = xcd * 8 + (s & 1) * 4 + (r & 3);
  const int bn = (s >> 1) * 4 + (r >> 2);

  const bf16* Ab = A + (size_t)bm * 256 * K;
  const bf16* Wb = W + (size_t)bn * 256 * K;

  const f32x4 fzero = {0.f, 0.f, 0.f, 0.f};
  f32x4 acc[8][4];
#pragma unroll
  for (int i2 = 0; i2 < 8; ++i2)
#pragma unroll
    for (int j = 0; j < 4; ++j) acc[i2][j] = fzero;

  size_t srcOff[2];
  int ldsOff[2];
#pragma unroll
  for (int i2 = 0; i2 < 2; ++i2) {
    const int c = i2 * 512 + tid;
    const int row = c >> 2, g = c & 3;
    const int gsrc = g ^ ((row >> 1) & 3);
    srcOff[i2] = (size_t)row * K + gsrc * 8;
    ldsOff[i2] = c * 8;
  }

  auto stageSlot = [&](int slot, int kh) {
#pragma unroll
    for (int i2 = 0; i2 < 2; ++i2)
      async16(Ab + srcOff[i2] + kh * 32, &As[slot][ldsOff[i2]]);
#pragma unroll
    for (int i2 = 0; i2 < 2; ++i2)
      async16(Wb + srcOff[i2] + kh * 32, &Bs[slot][ldsOff[i2]]);
  };

  auto compute = [&](int slot) {
    bf16x8 af[8], bf[4];
#pragma unroll
    for (int mf = 0; mf < 8; ++mf) {
      const int row = wm * 128 + mf * 16 + lo;
      const int g = hi ^ ((row >> 1) & 3);
      af[mf] = *(const bf16x8*)&As[slot][row * 32 + g * 8];
    }
#pragma unroll
    for (int nf = 0; nf < 4; ++nf) {
      const int row = wn * 64 + nf * 16 + lo;
      const int g = hi ^ ((row >> 1) & 3);
      bf[nf] = *(const bf16x8*)&Bs[slot][row * 32 + g * 8];
    }
    __builtin_amdgcn_s_setprio(1);
#pragma unroll
    for (int mf = 0; mf < 8; ++mf)
#pragma unroll
      for (int nf = 0; nf < 4; ++nf)
        acc[mf][nf] = MFMA16(af[mf], bf[nf], acc[mf][nf]);
    __builtin_amdgcn_s_setprio(0);
  };

  // prologue: slots 0,1 in flight (8 loads)
  stageSlot(0, 0);
  stageSlot(1, 1);

  // steady state: kh = 0..27
  for (int kt = 0; kt < 7; ++kt) {
#pragma unroll
    for (int ph = 0; ph < 4; ++ph) {
      stageSlot((ph + 2) & 3, kt * 4 + ph + 2);
      asm volatile("s_waitcnt vmcnt(8)" ::: "memory");
      __builtin_amdgcn_s_barrier();
      compute(ph);
    }
  }
  // tail: kh = 28..31
  stageSlot(2, 30);
  asm volatile("s_waitcnt vmcnt(8)" ::: "memory");
  __builtin_amdgcn_s_barrier();
  compute(0);
  stageSlot(3, 31);
  asm volatile("s_waitcnt vmcnt(8)" ::: "memory");
  __builtin_amdgcn_s_barrier();
  compute(1);
  asm volatile("s_waitcnt vmcnt(4)" ::: "memory");
  __builtin_amdgcn_s_barrier();
  compute(2);
  asm volatile("s_waitcnt vmcnt(0)" ::: "memory");
  __builtin_amdgcn_s_barrier();
  compute(3);

  const int rb0 = bm * 256 + wm * 128;
  const int jb0 = bn * 256 + wn * 64;

  if constexpr (EPI == 0) {
#pragma unroll
    for (int ac = 0; ac < 4; ++ac) {
      const int j = jb0 + ac * 16 + lo;
      const int which = j >> 10;        // 0=q 1=k 2=v (uniform per wave)
      const int f = j & 1023;
      const int h = f >> 6, d = f & 63; // d = ac*16+lo; d<32 <=> ac<2
#pragma unroll
      for (int ar = 0; ar < 8; ++ar) {
        const int rb = rb0 + ar * 16 + 4 * hi;
        f32x4 v = acc[ar][ac];
        if (which == 2) {
          // v transposed: vt[(b*16+h)*64 + d][n], 4 consecutive n -> 8B store
          const int b = rb >> 10, n0 = rb & 1023;
          bf16x4 pk = {(bf16)v[0], (bf16)v[1], (bf16)v[2], (bf16)v[3]};
          *(bf16x4*)(ovt + ((size_t)((b * 16 + h) * 64 + d)) * 1024 + n0) = pk;
        } else {
          bf16* dst = which ? okk : oq;
          const float sc = which ? 1.0f : QSCALE;
#pragma unroll
          for (int reg = 0; reg < 4; ++reg) {
            const int r2 = rb + reg;
            const int b = r2 >> 10, n = r2 & 1023;
            float val = v[reg];
            float res;
            if (d < 32) {
              float c = cosT[n * 32 + d];
              float sn = sinT[n * 32 + d];
              float pp = __shfl_xor(val, 1);  // rotary partner: adjacent lane = d^1
              res = (d & 1) ? fmaf(val, c, pp * sn) : fmaf(val, c, -(pp * sn));
            } else {
              res = val;
            }
            dst[((size_t)((b * 16 + h) * 1024 + n)) * 64 + d] = (bf16)(res * sc);
          }
        }
      }
    }
  } else {
#pragma unroll
    for (int ac = 0; ac < 4; ++ac) {
      const int j = jb0 + ac * 16 + lo;
      const float bv = bias[j];
#pragma unroll
      for (int ar = 0; ar < 8; ++ar) {
        const int rb = rb0 + ar * 16 + 4 * hi;
#pragma unroll
        for (int reg = 0; reg < 4; ++reg)
          outF[(size_t)(rb + reg) * 1024 + j] = acc[ar][ac][reg] + bv;
      }
    }
  }
}

// ---------------- flash attention: 8 waves x 32 q-rows (256 rows/block) -------
// K/V tiles [64][64] bf16 LINEAR in LDS, staged via global_load_lds with XOR
// swizzle (group g at row r holds global group g^(r&7); same XOR on read) ->
// conflict-free b128 reads, no VGPR round-trip for staging. Double-buffered
// with counted vmcnt(2). Each wave owns 32 q-rows: K/V fragments reused across
// both 16-row groups. Pt stride 68 elems: conflict-free b16 writes, 2-way reads.
// No max tracking: q pre-scaled by 1/8*log2e, P = exp2(S) directly; l-sum
// deferred to one post-loop shuffle reduction.
__global__ __launch_bounds__(512, 4) void attn_fwd(const bf16* __restrict__ q,
                                                   const bf16* __restrict__ k,
                                                   const bf16* __restrict__ vt,
                                                   bf16* __restrict__ o) {
  __shared__ bf16 Kt[2][64 * 64];
  __shared__ bf16 Vt[2][64 * 64];
  __shared__ bf16 Pt[8][32 * 68];
  const int tid = threadIdx.x;
  const int lane = tid & 63, wid = tid >> 6;
  const int lo = lane & 15, hi = lane >> 4;
  const int j = blockIdx.x;                  // 0..1023
  const int bh = (j & 7) + ((j >> 5) << 3);  // 0..255
  const int qt = (j >> 3) & 3;               // 0..3
  const bf16* qg = q + (size_t)bh * 65536;
  const bf16* kg = k + (size_t)bh * 65536;
  const bf16* vg = vt + (size_t)bh * 65536;

  bf16x8 qf[2][2];
#pragma unroll
  for (int rg = 0; rg < 2; ++rg) {
    const int qrow = qt * 256 + wid * 32 + rg * 16 + lo;
#pragma unroll
    for (int ch = 0; ch < 2; ++ch)
      qf[rg][ch] = *(const bf16x8*)(qg + (size_t)qrow * 64 + ch * 32 + 8 * hi);
  }

  const int srow = tid >> 3;
  const int sgsrc = (tid & 7) ^ (srow & 7);
  auto stageKV = [&](int buf, int kv) {
    async16(kg + (size_t)(kv * 64 + srow) * 64 + sgsrc * 8, &Kt[buf][tid * 8]);
    async16(vg + (size_t)srow * 1024 + kv * 64 + sgsrc * 8, &Vt[buf][tid * 8]);
  };

  asm volatile("s_waitcnt vmcnt(0)" ::: "memory");
  stageKV(0, 0);

  const f32x4 fzero = {0.f, 0.f, 0.f, 0.f};
  f32x4 of[2][4];
  float psum[2][4];
#pragma unroll
  for (int rg = 0; rg < 2; ++rg)
#pragma unroll
    for (int r = 0; r < 4; ++r) {
      of[rg][r] = fzero;
      psum[rg][r] = 0.f;
    }

  const int m7 = lo & 7;

  for (int kv = 0; kv < 16; ++kv) {
    const int cur = kv & 1;
    if (kv < 15) {
      stageKV(cur ^ 1, kv + 1);
      asm volatile("s_waitcnt vmcnt(2)" ::: "memory");
    } else {
      asm volatile("s_waitcnt vmcnt(0)" ::: "memory");
    }
    __builtin_amdgcn_s_barrier();

#pragma unroll
    for (int kf = 0; kf < 4; ++kf) {
      const int r = kf * 16 + lo;
      bf16x8 kb0 = *(const bf16x8*)&Kt[cur][r * 64 + ((hi ^ m7) * 8)];
      bf16x8 kb1 = *(const bf16x8*)&Kt[cur][r * 64 + (((hi + 4) ^ m7) * 8)];
#pragma unroll
      for (int rg = 0; rg < 2; ++rg) {
        f32x4 z = fzero;
        z = MFMA16(qf[rg][0], kb0, z);
        z = MFMA16(qf[rg][1], kb1, z);
#pragma unroll
        for (int reg = 0; reg < 4; ++reg) {
          float p = __builtin_amdgcn_exp2f(z[reg]);
          psum[rg][reg] += p;
          Pt[wid][(rg * 16 + 4 * hi + reg) * 68 + kf * 16 + lo] = (bf16)p;
        }
      }
    }

    bf16x8 pa[2][2];
#pragma unroll
    for (int rg = 0; rg < 2; ++rg)
#pragma unroll
      for (int ch = 0; ch < 2; ++ch)
        pa[rg][ch] = *(const bf16x8*)&Pt[wid][(rg * 16 + lo) * 68 + ch * 32 + 8 * hi];
#pragma unroll
    for (int df = 0; df < 4; ++df) {
      const int r = df * 16 + lo;
      bf16x8 vb0 = *(const bf16x8*)&Vt[cur][r * 64 + ((hi ^ m7) * 8)];
      bf16x8 vb1 = *(const bf16x8*)&Vt[cur][r * 64 + (((hi + 4) ^ m7) * 8)];
#pragma unroll
      for (int rg = 0; rg < 2; ++rg) {
        of[rg][df] = MFMA16(pa[rg][0], vb0, of[rg][df]);
        of[rg][df] = MFMA16(pa[rg][1], vb1, of[rg][df]);
      }
    }
    __syncthreads();
  }

#pragma unroll
  for (int off = 1; off < 16; off <<= 1) {
#pragma unroll
    for (int rg = 0; rg < 2; ++rg)
#pragma unroll
      for (int reg = 0; reg < 4; ++reg) psum[rg][reg] += __shfl_xor(psum[rg][reg], off);
  }

  const int b = bh >> 4, h = bh & 15;
#pragma unroll
  for (int rg = 0; rg < 2; ++rg)
#pragma unroll
    for (int reg = 0; reg < 4; ++reg) {
      const int n = qt * 256 + wid * 32 + rg * 16 + 4 * hi + reg;
      const float inv = 1.0f / psum[rg][reg];
#pragma unroll
      for (int df = 0; df < 4; ++df)
        o[((size_t)(b * 1024 + n)) * 1024 + h * 64 + df * 16 + lo] =
            (bf16)(of[rg][df][reg] * inv);
    }
}

extern "C" void kernel_launch(void* const* d_in, const int* in_sizes, int n_in,
                              void* d_out, int out_size, void* d_ws, size_t ws_size,
                              hipStream_t stream) {
  (void)in_sizes; (void)n_in; (void)out_size; (void)ws_size;
  const float* x = (const float*)d_in[0];
  const float* wqkv = (const float*)d_in[1];
  const float* wproj = (const float*)d_in[2];
  const float* bproj = (const float*)d_in[3];

  char* ws = (char*)d_ws;
  bf16* xb = (bf16*)(ws);                  // 33554432 B (x bf16; reused as attnout)
  bf16* wqb = (bf16*)(ws + 33554432);      // 6291456 B
  bf16* wpb = (bf16*)(ws + 39845888);      // 2097152 B
  float* cosT = (float*)(ws + 41943040);   // 131072 B
  float* sinT = (float*)(ws + 42074112);   // 131072 B
  bf16* qb = (bf16*)(ws + 42205184);       // 33554432 B  (b,h,n,d), pre-scaled
  bf16* kb = (bf16*)(ws + 75759616);       // 33554432 B  (b,h,n,d)
  bf16* vtb = (bf16*)(ws + 109314048);     // 33554432 B  (b,h,d,n)
  // total ws use: 142868480 B

  f2b_kernel<<<16384, 256, 0, stream>>>(x, xb, 16 * 1024 * 1024);
  f2b_kernel<<<3072, 256, 0, stream>>>(wqkv, wqb, 3 * 1024 * 1024);
  f2b_kernel<<<1024, 256, 0, stream>>>(wproj, wpb, 1024 * 1024);
  table_kernel<<<128, 256, 0, stream>>>(cosT, sinT);

  // QKV: M=16384, N=3072, K=1024 -> 64 bm x 12 bn = 768 blocks of 256x256
  gemm_bt<0, 12><<<768, 512, 0, stream>>>(xb, wqb, qb, kb, vtb, cosT, sinT,
                                          nullptr, nullptr);
  // attention: 1024 blocks (4 q-tiles x 256 heads, XCD-chunked), 8 waves each
  attn_fwd<<<1024, 512, 0, stream>>>(qb, kb, vtb, xb);
  // proj: M=16384, N=1024, K=1024 -> 64 bm x 4 bn = 256 blocks
  gemm_bt<1, 4><<<256, 512, 0, stream>>>(xb, wpb, nullptr, nullptr, nullptr,
                                         nullptr, nullptr, (float*)d_out, bproj);
}

// Round 5
// 275.624 us; speedup vs baseline: 7.7331x; 1.0113x over previous
//
#include <hip/hip_runtime.h>
#include <hip/hip_bf16.h>
#include <math.h>

typedef __bf16 bf16;
typedef bf16 bf16x4 __attribute__((ext_vector_type(4)));
typedef bf16 bf16x8 __attribute__((ext_vector_type(8)));
typedef float f32x4 __attribute__((ext_vector_type(4)));

#define MFMA16(a, b, c) __builtin_amdgcn_mfma_f32_16x16x32_bf16((a), (b), (c), 0, 0, 0)

// q pre-scale: 1/sqrt(64) * log2(e), folded into QKV epilogue so attention
// can use raw v_exp_f32 (exp2) with no per-score multiply.
#define QSCALE 0.18033688011112042f

// async global->LDS, 16B per lane. LDS dest is wave-uniform base + lane*16
// (linear); global src is per-lane (carries the swizzle).
__device__ __forceinline__ void async16(const void* g, void* l) {
  __builtin_amdgcn_global_load_lds(
      (const __attribute__((address_space(1))) void*)g,
      (__attribute__((address_space(3))) void*)l, 16, 0, 0);
}

#define BAR __builtin_amdgcn_s_barrier()
#define LGKM0 asm volatile("s_waitcnt lgkmcnt(0)" ::: "memory")
#define LGKM8 asm volatile("s_waitcnt lgkmcnt(8)" ::: "memory")
#define VMCNT(n) asm volatile("s_waitcnt vmcnt(" #n ")" ::: "memory")

// ---------------- fp32 -> bf16 conversion ----------------
__global__ __launch_bounds__(256) void f2b_kernel(const float* __restrict__ in,
                                                  bf16* __restrict__ out, int n) {
  int i = (blockIdx.x * 256 + threadIdx.x) * 4;
  if (i >= n) return;
  f32x4 v = *(const f32x4*)(in + i);
  bf16x4 o = {(bf16)v[0], (bf16)v[1], (bf16)v[2], (bf16)v[3]};
  *(bf16x4*)(out + i) = o;
}

// ---------------- axial RoPE cos/sin table: [n=1024][d=32] ----------------
__global__ __launch_bounds__(256) void table_kernel(float* __restrict__ cosT,
                                                    float* __restrict__ sinT) {
  int idx = blockIdx.x * 256 + threadIdx.x;
  if (idx >= 1024 * 32) return;
  int n = idx >> 5, d = idx & 31;
  int hf = n >> 5, wf = n & 31;
  int bi = (d & 15) >> 1;
  float base = (1.0f + 73.0f * bi) * 3.14159265358979323846f;  // linspace(1,512,8)[i]*pi
  int p = (d < 16) ? hf : wf;
  float pos = (2.0f * (float)p - 31.0f) * (1.0f / 31.0f);      // linspace(-1,1,32)
  float f = pos * base;
  cosT[idx] = cosf(f);
  sinT[idx] = sinf(f);
}

// ---------------- 256x256 8-wave GEMM, 8-phase T3+T4 schedule ----------------
// BK=64, 2 LDS buffers (tile kt -> buf kt&1), A/B each [2][256x64] (128KB).
// Iteration = 2 K-tiles = 8 phases. Per phase: read one A-quadrant (4 b128)
// [+ 8 B-frags at the tile's first phase, held in regs across its 4 phases],
// stage one 16KB half-tile (2 global_load_lds), then
// barrier; lgkmcnt(0); setprio(1); 16 MFMA; setprio(0); barrier.
// Counted vmcnt(6) ONLY at phases 4 and 8 (3 half-tiles stay in flight).
// Stage->phase map (iter t, tiles c0=2t,c1=2t+1, next n0=2t+2,n1=2t+3):
//   Ph1:A-q23(c1)  Ph2:B-h0(n0) Ph3:B-h1(n0) Ph4:A-q01(n0)+vmcnt6
//   Ph5:A-q23(n0)  Ph6:B-h0(n1) Ph7:B-h1(n1) Ph8:A-q01(n1)+vmcnt6
// Race-freedom (provable, no latency assumptions): every stage destination is
// >=2 barriers after its last reader, and readers pass lgkmcnt(0) BEFORE the
// MFMA-exit barrier, so reads are complete before any wave can reach the
// stage. Drain math: vmcnt(6)@Ph4 completes stages <=Ph1; @Ph8 <=Ph5; all
// consumption deadlines (B/A-q01 at a tile's Ph1, A-q23 at Ph3) satisfied.
// A-halves: q01 = rows wm*128+[0,64) (both wm), q23 = wm*128+[64,128).
// B-halves: h0 = rows [0,128), h1 = [128,256). Wave (wm,wn) touches only
// A-half wm / B-half wn>>1.
// REGISTER NOTE: stay at __launch_bounds__(512,2) — acc[8][4] = 128 AGPR +
// ~112 VGPR. (512,4) spills acc to scratch (round-3: 12x slowdown).
// Swizzle (128B rows, 8 groups): LDS (row,g) holds global group g^(row&7);
// read applies same XOR (pre-swizzled global source, linear LDS dest).
// Block map: XCD j owns bm stripe [8j,8j+8); 4x4 squares inside the stripe.
// EPI 0: QKV epilogue (RoPE on q,k; q pre-scaled; v transposed), NBN=12
// EPI 1: proj epilogue (bias add, fp32 out), NBN=4
template <int EPI, int NBN>
__global__ __launch_bounds__(512, 2) void gemm_bt(
    const bf16* __restrict__ A, const bf16* __restrict__ W,
    bf16* __restrict__ oq, bf16* __restrict__ okk, bf16* __restrict__ ovt,
    const float* __restrict__ cosT, const float* __restrict__ sinT,
    float* __restrict__ outF, const float* __restrict__ bias) {
  constexpr int K = 1024;
  __shared__ bf16 As[2][256 * 64];
  __shared__ bf16 Bs[2][256 * 64];

  const int tid = threadIdx.x;
  const int lane = tid & 63;
  const int wid = tid >> 6;          // 0..7
  const int lo = lane & 15, hi = lane >> 4;
  const int wm = wid >> 2;           // 0..1 (M half)
  const int wn = wid & 3;            // 0..3 (N quarter)

  // XCD-stripe block mapping with 4x4 square ordering inside the stripe.
  const int wg = blockIdx.x;
  const int xcd = wg & 7;
  const int i = wg >> 3;             // 0 .. 8*NBN-1
  const int s4 = i >> 4;             // square index
  const int r4 = i & 15;
  const int bm = xcd * 8 + (s4 & 1) * 4 + (r4 & 3);
  const int bn = (s4 >> 1) * 4 + (r4 >> 2);

  const bf16* Ab = A + (size_t)bm * 256 * K;
  const bf16* Wb = W + (size_t)bn * 256 * K;

  const f32x4 fzero = {0.f, 0.f, 0.f, 0.f};
  f32x4 acc[8][4];
#pragma unroll
  for (int i2 = 0; i2 < 8; ++i2)
#pragma unroll
    for (int j = 0; j < 4; ++j) acc[i2][j] = fzero;

  // ---- staging: one 16KB half-tile = 2 async16 per thread ----
  // rr in [0,64): 8 consecutive lanes share a row; row&7 == lane>>3 pattern
  const int rr = (wid << 3) + ((lane >> 3) & 7);  // wid*8 + lane/8
  const int sg = lane & 7;
  auto stA = [&](int buf, int kt, int q23) {
#pragma unroll
    for (int i2 = 0; i2 < 2; ++i2) {
      const int row = q23 * 64 + i2 * 128 + rr;
      async16(Ab + (size_t)row * K + kt * 64 + (sg ^ (row & 7)) * 8,
              &As[buf][row * 64 + sg * 8]);
    }
  };
  auto stB = [&](int buf, int kt, int h) {
#pragma unroll
    for (int i2 = 0; i2 < 2; ++i2) {
      const int row = h * 128 + i2 * 64 + rr;
      async16(Wb + (size_t)row * K + kt * 64 + (sg ^ (row & 7)) * 8,
              &Bs[buf][row * 64 + sg * 8]);
    }
  };

  // ---- fragment reads (swizzled) ----
  auto readA = [&](int buf, int mf, int s) -> bf16x8 {
    const int row = wm * 128 + mf * 16 + lo;
    const int g = (s * 4 + hi) ^ (lo & 7);
    return *(const bf16x8*)&As[buf][row * 64 + g * 8];
  };
  auto readB = [&](int buf, int nf, int s) -> bf16x8 {
    const int row = wn * 64 + nf * 16 + lo;
    const int g = (s * 4 + hi) ^ (lo & 7);
    return *(const bf16x8*)&Bs[buf][row * 64 + g * 8];
  };

  bf16x8 bfr[4][2];  // B-frags, held across a tile's 4 phases
  bf16x8 a[2][2];    // current A-quadrant frags
  auto rdq = [&](int buf, int p) {
#pragma unroll
    for (int mi = 0; mi < 2; ++mi)
#pragma unroll
      for (int s = 0; s < 2; ++s) a[mi][s] = readA(buf, 2 * p + mi, s);
  };
  auto rdb = [&](int buf) {
#pragma unroll
    for (int nf = 0; nf < 4; ++nf)
#pragma unroll
      for (int s = 0; s < 2; ++s) bfr[nf][s] = readB(buf, nf, s);
  };
  auto mma = [&](int p) {
    __builtin_amdgcn_s_setprio(1);
#pragma unroll
    for (int mi = 0; mi < 2; ++mi)
#pragma unroll
      for (int nf = 0; nf < 4; ++nf)
#pragma unroll
        for (int s = 0; s < 2; ++s)
          acc[2 * p + mi][nf] = MFMA16(a[mi][s], bfr[nf][s], acc[2 * p + mi][nf]);
    __builtin_amdgcn_s_setprio(0);
  };

  // ---- prologue: tile0 fully + tile1 (B, A-q01); tile1 A-q23 comes at Ph1 ----
  stB(0, 0, 0); stB(0, 0, 1); stA(0, 0, 0); stA(0, 0, 1);
  stB(1, 1, 0); stB(1, 1, 1); stA(1, 1, 0);
  VMCNT(0);
  BAR;

  // ---- main loop: iters t=0..6 compute tiles 2t,2t+1; stage 2t+2,2t+3 ----
  for (int t = 0; t < 7; ++t) {
    const int c1 = 2 * t + 1, n0 = 2 * t + 2, n1 = 2 * t + 3;
    // Ph1
    rdq(0, 0); rdb(0); stA(1, c1, 1);
    LGKM8; BAR; LGKM0; mma(0); BAR;
    // Ph2
    rdq(0, 1); stB(0, n0, 0); BAR; LGKM0; mma(1); BAR;
    // Ph3
    rdq(0, 2); stB(0, n0, 1); BAR; LGKM0; mma(2); BAR;
    // Ph4
    rdq(0, 3); stA(0, n0, 0); VMCNT(6); BAR; LGKM0; mma(3); BAR;
    // Ph5
    rdq(1, 0); rdb(1); stA(0, n0, 1);
    LGKM8; BAR; LGKM0; mma(0); BAR;
    // Ph6
    rdq(1, 1); stB(1, n1, 0); BAR; LGKM0; mma(1); BAR;
    // Ph7
    rdq(1, 2); stB(1, n1, 1); BAR; LGKM0; mma(2); BAR;
    // Ph8
    rdq(1, 3); stA(1, n1, 0); VMCNT(6); BAR; LGKM0; mma(3); BAR;
  }
  // ---- tail iter: tiles 14,15; only Ph1's stage (A-q23 of tile 15) ----
  rdq(0, 0); rdb(0); stA(1, 15, 1);
  LGKM8; BAR; LGKM0; mma(0); BAR;
  rdq(0, 1); BAR; LGKM0; mma(1); BAR;
  rdq(0, 2); BAR; LGKM0; mma(2); BAR;
  rdq(0, 3); VMCNT(0); BAR; LGKM0; mma(3); BAR;
  rdq(1, 0); rdb(1); BAR; LGKM0; mma(0); BAR;
  rdq(1, 1); BAR; LGKM0; mma(1); BAR;
  rdq(1, 2); BAR; LGKM0; mma(2); BAR;
  rdq(1, 3); LGKM0; mma(3);

  const int rb0 = bm * 256 + wm * 128;
  const int jb0 = bn * 256 + wn * 64;

  if constexpr (EPI == 0) {
#pragma unroll
    for (int ac = 0; ac < 4; ++ac) {
      const int j = jb0 + ac * 16 + lo;
      const int which = j >> 10;        // 0=q 1=k 2=v (uniform per wave)
      const int f = j & 1023;
      const int h = f >> 6, d = f & 63; // d = ac*16+lo; d<32 <=> ac<2
#pragma unroll
      for (int ar = 0; ar < 8; ++ar) {
        const int rb = rb0 + ar * 16 + 4 * hi;
        f32x4 v = acc[ar][ac];
        if (which == 2) {
          // v transposed: vt[(b*16+h)*64 + d][n], 4 consecutive n -> 8B store
          const int b = rb >> 10, n0 = rb & 1023;
          bf16x4 pk = {(bf16)v[0], (bf16)v[1], (bf16)v[2], (bf16)v[3]};
          *(bf16x4*)(ovt + ((size_t)((b * 16 + h) * 64 + d)) * 1024 + n0) = pk;
        } else {
          bf16* dst = which ? okk : oq;
          const float sc = which ? 1.0f : QSCALE;
#pragma unroll
          for (int reg = 0; reg < 4; ++reg) {
            const int r2 = rb + reg;
            const int b = r2 >> 10, n = r2 & 1023;
            float val = v[reg];
            float res;
            if (d < 32) {
              float c = cosT[n * 32 + d];
              float sn = sinT[n * 32 + d];
              float pp = __shfl_xor(val, 1);  // rotary partner: adjacent lane = d^1
              res = (d & 1) ? fmaf(val, c, pp * sn) : fmaf(val, c, -(pp * sn));
            } else {
              res = val;
            }
            dst[((size_t)((b * 16 + h) * 1024 + n)) * 64 + d] = (bf16)(res * sc);
          }
        }
      }
    }
  } else {
#pragma unroll
    for (int ac = 0; ac < 4; ++ac) {
      const int j = jb0 + ac * 16 + lo;
      const float bv = bias[j];
#pragma unroll
      for (int ar = 0; ar < 8; ++ar) {
        const int rb = rb0 + ar * 16 + 4 * hi;
#pragma unroll
        for (int reg = 0; reg < 4; ++reg)
          outF[(size_t)(rb + reg) * 1024 + j] = acc[ar][ac][reg] + bv;
      }
    }
  }
}

// ---------------- flash attention: 8 waves x 32 q-rows (256 rows/block) -------
// (unchanged from round 2 — verified at ~90us)
__global__ __launch_bounds__(512, 4) void attn_fwd(const bf16* __restrict__ q,
                                                   const bf16* __restrict__ k,
                                                   const bf16* __restrict__ vt,
                                                   bf16* __restrict__ o) {
  __shared__ bf16 Kt[2][64 * 64];
  __shared__ bf16 Vt[2][64 * 64];
  __shared__ bf16 Pt[8][32 * 68];
  const int tid = threadIdx.x;
  const int lane = tid & 63, wid = tid >> 6;
  const int lo = lane & 15, hi = lane >> 4;
  const int j = blockIdx.x;                  // 0..1023
  const int bh = (j & 7) + ((j >> 5) << 3);  // 0..255
  const int qt = (j >> 3) & 3;               // 0..3
  const bf16* qg = q + (size_t)bh * 65536;
  const bf16* kg = k + (size_t)bh * 65536;
  const bf16* vg = vt + (size_t)bh * 65536;

  bf16x8 qf[2][2];
#pragma unroll
  for (int rg = 0; rg < 2; ++rg) {
    const int qrow = qt * 256 + wid * 32 + rg * 16 + lo;
#pragma unroll
    for (int ch = 0; ch < 2; ++ch)
      qf[rg][ch] = *(const bf16x8*)(qg + (size_t)qrow * 64 + ch * 32 + 8 * hi);
  }

  const int srow = tid >> 3;
  const int sgsrc = (tid & 7) ^ (srow & 7);
  auto stageKV = [&](int buf, int kv) {
    async16(kg + (size_t)(kv * 64 + srow) * 64 + sgsrc * 8, &Kt[buf][tid * 8]);
    async16(vg + (size_t)srow * 1024 + kv * 64 + sgsrc * 8, &Vt[buf][tid * 8]);
  };

  asm volatile("s_waitcnt vmcnt(0)" ::: "memory");
  stageKV(0, 0);

  const f32x4 fzero = {0.f, 0.f, 0.f, 0.f};
  f32x4 of[2][4];
  float psum[2][4];
#pragma unroll
  for (int rg = 0; rg < 2; ++rg)
#pragma unroll
    for (int r = 0; r < 4; ++r) {
      of[rg][r] = fzero;
      psum[rg][r] = 0.f;
    }

  const int m7 = lo & 7;

  for (int kv = 0; kv < 16; ++kv) {
    const int cur = kv & 1;
    if (kv < 15) {
      stageKV(cur ^ 1, kv + 1);
      asm volatile("s_waitcnt vmcnt(2)" ::: "memory");
    } else {
      asm volatile("s_waitcnt vmcnt(0)" ::: "memory");
    }
    __builtin_amdgcn_s_barrier();

#pragma unroll
    for (int kf = 0; kf < 4; ++kf) {
      const int r = kf * 16 + lo;
      bf16x8 kb0 = *(const bf16x8*)&Kt[cur][r * 64 + ((hi ^ m7) * 8)];
      bf16x8 kb1 = *(const bf16x8*)&Kt[cur][r * 64 + (((hi + 4) ^ m7) * 8)];
#pragma unroll
      for (int rg = 0; rg < 2; ++rg) {
        f32x4 z = fzero;
        z = MFMA16(qf[rg][0], kb0, z);
        z = MFMA16(qf[rg][1], kb1, z);
#pragma unroll
        for (int reg = 0; reg < 4; ++reg) {
          float p = __builtin_amdgcn_exp2f(z[reg]);
          psum[rg][reg] += p;
          Pt[wid][(rg * 16 + 4 * hi + reg) * 68 + kf * 16 + lo] = (bf16)p;
        }
      }
    }

    bf16x8 pa[2][2];
#pragma unroll
    for (int rg = 0; rg < 2; ++rg)
#pragma unroll
      for (int ch = 0; ch < 2; ++ch)
        pa[rg][ch] = *(const bf16x8*)&Pt[wid][(rg * 16 + lo) * 68 + ch * 32 + 8 * hi];
#pragma unroll
    for (int df = 0; df < 4; ++df) {
      const int r = df * 16 + lo;
      bf16x8 vb0 = *(const bf16x8*)&Vt[cur][r * 64 + ((hi ^ m7) * 8)];
      bf16x8 vb1 = *(const bf16x8*)&Vt[cur][r * 64 + (((hi + 4) ^ m7) * 8)];
#pragma unroll
      for (int rg = 0; rg < 2; ++rg) {
        of[rg][df] = MFMA16(pa[rg][0], vb0, of[rg][df]);
        of[rg][df] = MFMA16(pa[rg][1], vb1, of[rg][df]);
      }
    }
    __syncthreads();
  }

#pragma unroll
  for (int off = 1; off < 16; off <<= 1) {
#pragma unroll
    for (int rg = 0; rg < 2; ++rg)
#pragma unroll
      for (int reg = 0; reg < 4; ++reg) psum[rg][reg] += __shfl_xor(psum[rg][reg], off);
  }

  const int b = bh >> 4, h = bh & 15;
#pragma unroll
  for (int rg = 0; rg < 2; ++rg)
#pragma unroll
    for (int reg = 0; reg < 4; ++reg) {
      const int n = qt * 256 + wid * 32 + rg * 16 + 4 * hi + reg;
      const float inv = 1.0f / psum[rg][reg];
#pragma unroll
      for (int df = 0; df < 4; ++df)
        o[((size_t)(b * 1024 + n)) * 1024 + h * 64 + df * 16 + lo] =
            (bf16)(of[rg][df][reg] * inv);
    }
}

extern "C" void kernel_launch(void* const* d_in, const int* in_sizes, int n_in,
                              void* d_out, int out_size, void* d_ws, size_t ws_size,
                              hipStream_t stream) {
  (void)in_sizes; (void)n_in; (void)out_size; (void)ws_size;
  const float* x = (const float*)d_in[0];
  const float* wqkv = (const float*)d_in[1];
  const float* wproj = (const float*)d_in[2];
  const float* bproj = (const float*)d_in[3];

  char* ws = (char*)d_ws;
  bf16* xb = (bf16*)(ws);                  // 33554432 B (x bf16; reused as attnout)
  bf16* wqb = (bf16*)(ws + 33554432);      // 6291456 B
  bf16* wpb = (bf16*)(ws + 39845888);      // 2097152 B
  float* cosT = (float*)(ws + 41943040);   // 131072 B
  float* sinT = (float*)(ws + 42074112);   // 131072 B
  bf16* qb = (bf16*)(ws + 42205184);       // 33554432 B  (b,h,n,d), pre-scaled
  bf16* kb = (bf16*)(ws + 75759616);       // 33554432 B  (b,h,n,d)
  bf16* vtb = (bf16*)(ws + 109314048);     // 33554432 B  (b,h,d,n)
  // total ws use: 142868480 B

  f2b_kernel<<<16384, 256, 0, stream>>>(x, xb, 16 * 1024 * 1024);
  f2b_kernel<<<3072, 256, 0, stream>>>(wqkv, wqb, 3 * 1024 * 1024);
  f2b_kernel<<<1024, 256, 0, stream>>>(wproj, wpb, 1024 * 1024);
  table_kernel<<<128, 256, 0, stream>>>(cosT, sinT);

  // QKV: M=16384, N=3072, K=1024 -> 64 bm x 12 bn = 768 blocks of 256x256
  gemm_bt<0, 12><<<768, 512, 0, stream>>>(xb, wqb, qb, kb, vtb, cosT, sinT,
                                          nullptr, nullptr);
  // attention: 1024 blocks (4 q-tiles x 256 heads, XCD-chunked), 8 waves each
  attn_fwd<<<1024, 512, 0, stream>>>(qb, kb, vtb, xb);
  // proj: M=16384, N=1024, K=1024 -> 64 bm x 4 bn = 256 blocks
  gemm_bt<1, 4><<<256, 512, 0, stream>>>(xb, wpb, nullptr, nullptr, nullptr,
                                         nullptr, nullptr, (float*)d_out, bproj);
}

// Round 6
// 273.163 us; speedup vs baseline: 7.8027x; 1.0090x over previous
//
#include <hip/hip_runtime.h>
#include <hip/hip_bf16.h>
#include <math.h>

typedef __bf16 bf16;
typedef bf16 bf16x4 __attribute__((ext_vector_type(4)));
typedef bf16 bf16x8 __attribute__((ext_vector_type(8)));
typedef float f32x4 __attribute__((ext_vector_type(4)));

#define MFMA16(a, b, c) __builtin_amdgcn_mfma_f32_16x16x32_bf16((a), (b), (c), 0, 0, 0)

// q pre-scale: 1/sqrt(64) * log2(e), folded into QKV epilogue so attention
// can use raw v_exp_f32 (exp2) with no per-score multiply.
#define QSCALE 0.18033688011112042f

// async global->LDS, 16B per lane. LDS dest is wave-uniform base + lane*16
// (linear); global src is per-lane (carries the swizzle).
__device__ __forceinline__ void async16(const void* g, void* l) {
  __builtin_amdgcn_global_load_lds(
      (const __attribute__((address_space(1))) void*)g,
      (__attribute__((address_space(3))) void*)l, 16, 0, 0);
}

// ---------------- fp32 -> bf16 conversion, all three tensors in one launch ----
// ranges: x 16M elems, wqkv 3M, wproj 1M (threads*4 elems each)
__global__ __launch_bounds__(256) void f2b_all_kernel(const float* __restrict__ x,
                                                      const float* __restrict__ wqkv,
                                                      const float* __restrict__ wproj,
                                                      bf16* __restrict__ xb,
                                                      bf16* __restrict__ wqb,
                                                      bf16* __restrict__ wpb) {
  int t = blockIdx.x * 256 + threadIdx.x;  // 0 .. 5M-1
  const float* in;
  bf16* out;
  int i;
  if (t < 4194304) {            // x: 16M elems
    in = x; out = xb; i = t * 4;
  } else if (t < 4980736) {     // wqkv: 3M elems
    in = wqkv; out = wqb; i = (t - 4194304) * 4;
  } else {                      // wproj: 1M elems
    in = wproj; out = wpb; i = (t - 4980736) * 4;
  }
  f32x4 v = *(const f32x4*)(in + i);
  bf16x4 o = {(bf16)v[0], (bf16)v[1], (bf16)v[2], (bf16)v[3]};
  *(bf16x4*)(out + i) = o;
}

// ---------------- axial RoPE cos/sin table: [n=1024][d=32] ----------------
__global__ __launch_bounds__(256) void table_kernel(float* __restrict__ cosT,
                                                    float* __restrict__ sinT) {
  int idx = blockIdx.x * 256 + threadIdx.x;
  if (idx >= 1024 * 32) return;
  int n = idx >> 5, d = idx & 31;
  int hf = n >> 5, wf = n & 31;
  int bi = (d & 15) >> 1;
  float base = (1.0f + 73.0f * bi) * 3.14159265358979323846f;  // linspace(1,512,8)[i]*pi
  int p = (d < 16) ? hf : wf;
  float pos = (2.0f * (float)p - 31.0f) * (1.0f / 31.0f);      // linspace(-1,1,32)
  float f = pos * base;
  cosT[idx] = cosf(f);
  sinT[idx] = sinf(f);
}

// ---------------- 256x256 8-wave GEMM, 32-phase counted-vmcnt pipeline ----------
// A: MxK row-major, W: NxK row-major. Phase = one K-half (BK=32). LDS is a
// 4-slot ring per matrix (slot kh -> kh&3, 16KB each, 128KB total). Phase kh:
//   issue stage of slot kh+2 (4 global_load_lds), s_waitcnt vmcnt(8)  [counted:
//   forces only slot kh's 4 oldest loads; 8 stay in flight across the barrier],
//   barrier, ds_read 12 frags, 32 MFMA (setprio-wrapped).
// Race-freedom: slot (kh+2)&3's tenant kh-2 was fully read (its MFMA precedes
// barrier(kh-1)) before any wave issues the stage at phase kh. One barrier per
// phase; vmcnt hits 0 only at the last phase.
// VERIFIED BEST (R4: QKV 127.8us, MfmaUtil 34%, VGPR 112, conflicts 0).
// R5's 8-phase port regressed (134us, util 31%): K=1024 has only 16 K-tiles so
// fill/drain is ~25% of the loop, and 2-barriers/phase + frag-holding VGPR
// pressure ate the phase-interleave gain. Do not re-attempt without new theory.
// REGISTER NOTE: must stay at __launch_bounds__(512,2) — acc[8][4] lives as 128
// AGPRs + ~112 VGPRs = 240/256. (512,4) halves the budget and spills acc to
// scratch (round-3 post-mortem: 2.4GB scratch FETCH, 12x slowdown).
// Swizzle (64B rows): LDS (row, g16) holds global group g16^((row>>1)&3); read
// applies same XOR (pre-swizzled global source, linear LDS dest).
// Block map: XCD j owns bm stripe [8j,8j+8); within the stripe, blocks are
// ordered in 4bm x 4bn squares so the ~32 concurrent blocks per XCD touch
// ~4 A-panels + 4 B-panels (~4MB) instead of 3A + NBN B (7.5MB > 4MB L2).
// EPI 0: QKV epilogue (RoPE on q,k; q pre-scaled; v transposed (b,h,d,n)), NBN=12
// EPI 1: proj epilogue (bias add, fp32 out), NBN=4
template <int EPI, int NBN>
__global__ __launch_bounds__(512, 2) void gemm_bt(
    const bf16* __restrict__ A, const bf16* __restrict__ W,
    bf16* __restrict__ oq, bf16* __restrict__ okk, bf16* __restrict__ ovt,
    const float* __restrict__ cosT, const float* __restrict__ sinT,
    float* __restrict__ outF, const float* __restrict__ bias) {
  constexpr int K = 1024;
  __shared__ bf16 As[4][256 * 32];
  __shared__ bf16 Bs[4][256 * 32];

  const int tid = threadIdx.x;
  const int lane = tid & 63;
  const int wid = tid >> 6;          // 0..7
  const int lo = lane & 15, hi = lane >> 4;
  const int wm = wid >> 2;           // 0..1 (M half)
  const int wn = wid & 3;            // 0..3 (N quarter)

  // XCD-stripe block mapping with 4x4 square ordering inside the stripe.
  const int wg = blockIdx.x;
  const int xcd = wg & 7;
  const int i = wg >> 3;             // 0 .. 8*NBN-1
  const int s = i >> 4;              // square index: (s&1)=bm half, (s>>1)=bn quad
  const int r = i & 15;
  const int bm = xcd * 8 + (s & 1) * 4 + (r & 3);
  const int bn = (s >> 1) * 4 + (r >> 2);

  const bf16* Ab = A + (size_t)bm * 256 * K;
  const bf16* Wb = W + (size_t)bn * 256 * K;

  const f32x4 fzero = {0.f, 0.f, 0.f, 0.f};
  f32x4 acc[8][4];
#pragma unroll
  for (int i2 = 0; i2 < 8; ++i2)
#pragma unroll
    for (int j = 0; j < 4; ++j) acc[i2][j] = fzero;

  size_t srcOff[2];
  int ldsOff[2];
#pragma unroll
  for (int i2 = 0; i2 < 2; ++i2) {
    const int c = i2 * 512 + tid;
    const int row = c >> 2, g = c & 3;
    const int gsrc = g ^ ((row >> 1) & 3);
    srcOff[i2] = (size_t)row * K + gsrc * 8;
    ldsOff[i2] = c * 8;
  }

  auto stageSlot = [&](int slot, int kh) {
#pragma unroll
    for (int i2 = 0; i2 < 2; ++i2)
      async16(Ab + srcOff[i2] + kh * 32, &As[slot][ldsOff[i2]]);
#pragma unroll
    for (int i2 = 0; i2 < 2; ++i2)
      async16(Wb + srcOff[i2] + kh * 32, &Bs[slot][ldsOff[i2]]);
  };

  auto compute = [&](int slot) {
    bf16x8 af[8], bf[4];
#pragma unroll
    for (int mf = 0; mf < 8; ++mf) {
      const int row = wm * 128 + mf * 16 + lo;
      const int g = hi ^ ((row >> 1) & 3);
      af[mf] = *(const bf16x8*)&As[slot][row * 32 + g * 8];
    }
#pragma unroll
    for (int nf = 0; nf < 4; ++nf) {
      const int row = wn * 64 + nf * 16 + lo;
      const int g = hi ^ ((row >> 1) & 3);
      bf[nf] = *(const bf16x8*)&Bs[slot][row * 32 + g * 8];
    }
    __builtin_amdgcn_s_setprio(1);
#pragma unroll
    for (int mf = 0; mf < 8; ++mf)
#pragma unroll
      for (int nf = 0; nf < 4; ++nf)
        acc[mf][nf] = MFMA16(af[mf], bf[nf], acc[mf][nf]);
    __builtin_amdgcn_s_setprio(0);
  };

  // prologue: slots 0,1 in flight (8 loads)
  stageSlot(0, 0);
  stageSlot(1, 1);

  // steady state: kh = 0..27
  for (int kt = 0; kt < 7; ++kt) {
#pragma unroll
    for (int ph = 0; ph < 4; ++ph) {
      stageSlot((ph + 2) & 3, kt * 4 + ph + 2);
      asm volatile("s_waitcnt vmcnt(8)" ::: "memory");
      __builtin_amdgcn_s_barrier();
      compute(ph);
    }
  }
  // tail: kh = 28..31
  stageSlot(2, 30);
  asm volatile("s_waitcnt vmcnt(8)" ::: "memory");
  __builtin_amdgcn_s_barrier();
  compute(0);
  stageSlot(3, 31);
  asm volatile("s_waitcnt vmcnt(8)" ::: "memory");
  __builtin_amdgcn_s_barrier();
  compute(1);
  asm volatile("s_waitcnt vmcnt(4)" ::: "memory");
  __builtin_amdgcn_s_barrier();
  compute(2);
  asm volatile("s_waitcnt vmcnt(0)" ::: "memory");
  __builtin_amdgcn_s_barrier();
  compute(3);

  const int rb0 = bm * 256 + wm * 128;
  const int jb0 = bn * 256 + wn * 64;

  if constexpr (EPI == 0) {
#pragma unroll
    for (int ac = 0; ac < 4; ++ac) {
      const int j = jb0 + ac * 16 + lo;
      const int which = j >> 10;        // 0=q 1=k 2=v (uniform per wave)
      const int f = j & 1023;
      const int h = f >> 6, d = f & 63; // d = ac*16+lo; d<32 <=> ac<2
#pragma unroll
      for (int ar = 0; ar < 8; ++ar) {
        const int rb = rb0 + ar * 16 + 4 * hi;
        f32x4 v = acc[ar][ac];
        if (which == 2) {
          // v transposed: vt[(b*16+h)*64 + d][n], 4 consecutive n -> 8B store
          const int b = rb >> 10, n0 = rb & 1023;
          bf16x4 pk = {(bf16)v[0], (bf16)v[1], (bf16)v[2], (bf16)v[3]};
          *(bf16x4*)(ovt + ((size_t)((b * 16 + h) * 64 + d)) * 1024 + n0) = pk;
        } else {
          bf16* dst = which ? okk : oq;
          const float sc = which ? 1.0f : QSCALE;
#pragma unroll
          for (int reg = 0; reg < 4; ++reg) {
            const int r2 = rb + reg;
            const int b = r2 >> 10, n = r2 & 1023;
            float val = v[reg];
            float res;
            if (d < 32) {
              float c = cosT[n * 32 + d];
              float sn = sinT[n * 32 + d];
              float pp = __shfl_xor(val, 1);  // rotary partner: adjacent lane = d^1
              res = (d & 1) ? fmaf(val, c, pp * sn) : fmaf(val, c, -(pp * sn));
            } else {
              res = val;
            }
            dst[((size_t)((b * 16 + h) * 1024 + n)) * 64 + d] = (bf16)(res * sc);
          }
        }
      }
    }
  } else {
#pragma unroll
    for (int ac = 0; ac < 4; ++ac) {
      const int j = jb0 + ac * 16 + lo;
      const float bv = bias[j];
#pragma unroll
      for (int ar = 0; ar < 8; ++ar) {
        const int rb = rb0 + ar * 16 + 4 * hi;
#pragma unroll
        for (int reg = 0; reg < 4; ++reg)
          outF[(size_t)(rb + reg) * 1024 + j] = acc[ar][ac][reg] + bv;
      }
    }
  }
}

// ---------------- flash attention: 8 waves x 32 q-rows (256 rows/block) -------
// K/V tiles [64][64] bf16 LINEAR in LDS, staged via global_load_lds with XOR
// swizzle (group g at row r holds global group g^(r&7); same XOR on read) ->
// conflict-free b128 reads, no VGPR round-trip for staging. Double-buffered
// with counted vmcnt(2). Each wave owns 32 q-rows: K/V fragments reused across
// both 16-row groups. Pt stride 68 elems: conflict-free b16 writes, 2-way reads.
// No max tracking: q pre-scaled by 1/8*log2e, P = exp2(S) directly; l-sum
// deferred to one post-loop shuffle reduction.
__global__ __launch_bounds__(512, 4) void attn_fwd(const bf16* __restrict__ q,
                                                   const bf16* __restrict__ k,
                                                   const bf16* __restrict__ vt,
                                                   bf16* __restrict__ o) {
  __shared__ bf16 Kt[2][64 * 64];
  __shared__ bf16 Vt[2][64 * 64];
  __shared__ bf16 Pt[8][32 * 68];
  const int tid = threadIdx.x;
  const int lane = tid & 63, wid = tid >> 6;
  const int lo = lane & 15, hi = lane >> 4;
  const int j = blockIdx.x;                  // 0..1023
  const int bh = (j & 7) + ((j >> 5) << 3);  // 0..255
  const int qt = (j >> 3) & 3;               // 0..3
  const bf16* qg = q + (size_t)bh * 65536;
  const bf16* kg = k + (size_t)bh * 65536;
  const bf16* vg = vt + (size_t)bh * 65536;

  bf16x8 qf[2][2];
#pragma unroll
  for (int rg = 0; rg < 2; ++rg) {
    const int qrow = qt * 256 + wid * 32 + rg * 16 + lo;
#pragma unroll
    for (int ch = 0; ch < 2; ++ch)
      qf[rg][ch] = *(const bf16x8*)(qg + (size_t)qrow * 64 + ch * 32 + 8 * hi);
  }

  const int srow = tid >> 3;
  const int sgsrc = (tid & 7) ^ (srow & 7);
  auto stageKV = [&](int buf, int kv) {
    async16(kg + (size_t)(kv * 64 + srow) * 64 + sgsrc * 8, &Kt[buf][tid * 8]);
    async16(vg + (size_t)srow * 1024 + kv * 64 + sgsrc * 8, &Vt[buf][tid * 8]);
  };

  asm volatile("s_waitcnt vmcnt(0)" ::: "memory");
  stageKV(0, 0);

  const f32x4 fzero = {0.f, 0.f, 0.f, 0.f};
  f32x4 of[2][4];
  float psum[2][4];
#pragma unroll
  for (int rg = 0; rg < 2; ++rg)
#pragma unroll
    for (int r = 0; r < 4; ++r) {
      of[rg][r] = fzero;
      psum[rg][r] = 0.f;
    }

  const int m7 = lo & 7;

  for (int kv = 0; kv < 16; ++kv) {
    const int cur = kv & 1;
    if (kv < 15) {
      stageKV(cur ^ 1, kv + 1);
      asm volatile("s_waitcnt vmcnt(2)" ::: "memory");
    } else {
      asm volatile("s_waitcnt vmcnt(0)" ::: "memory");
    }
    __builtin_amdgcn_s_barrier();

#pragma unroll
    for (int kf = 0; kf < 4; ++kf) {
      const int r = kf * 16 + lo;
      bf16x8 kb0 = *(const bf16x8*)&Kt[cur][r * 64 + ((hi ^ m7) * 8)];
      bf16x8 kb1 = *(const bf16x8*)&Kt[cur][r * 64 + (((hi + 4) ^ m7) * 8)];
#pragma unroll
      for (int rg = 0; rg < 2; ++rg) {
        f32x4 z = fzero;
        z = MFMA16(qf[rg][0], kb0, z);
        z = MFMA16(qf[rg][1], kb1, z);
#pragma unroll
        for (int reg = 0; reg < 4; ++reg) {
          float p = __builtin_amdgcn_exp2f(z[reg]);
          psum[rg][reg] += p;
          Pt[wid][(rg * 16 + 4 * hi + reg) * 68 + kf * 16 + lo] = (bf16)p;
        }
      }
    }

    bf16x8 pa[2][2];
#pragma unroll
    for (int rg = 0; rg < 2; ++rg)
#pragma unroll
      for (int ch = 0; ch < 2; ++ch)
        pa[rg][ch] = *(const bf16x8*)&Pt[wid][(rg * 16 + lo) * 68 + ch * 32 + 8 * hi];
#pragma unroll
    for (int df = 0; df < 4; ++df) {
      const int r = df * 16 + lo;
      bf16x8 vb0 = *(const bf16x8*)&Vt[cur][r * 64 + ((hi ^ m7) * 8)];
      bf16x8 vb1 = *(const bf16x8*)&Vt[cur][r * 64 + (((hi + 4) ^ m7) * 8)];
#pragma unroll
      for (int rg = 0; rg < 2; ++rg) {
        of[rg][df] = MFMA16(pa[rg][0], vb0, of[rg][df]);
        of[rg][df] = MFMA16(pa[rg][1], vb1, of[rg][df]);
      }
    }
    __syncthreads();
  }

#pragma unroll
  for (int off = 1; off < 16; off <<= 1) {
#pragma unroll
    for (int rg = 0; rg < 2; ++rg)
#pragma unroll
      for (int reg = 0; reg < 4; ++reg) psum[rg][reg] += __shfl_xor(psum[rg][reg], off);
  }

  const int b = bh >> 4, h = bh & 15;
#pragma unroll
  for (int rg = 0; rg < 2; ++rg)
#pragma unroll
    for (int reg = 0; reg < 4; ++reg) {
      const int n = qt * 256 + wid * 32 + rg * 16 + 4 * hi + reg;
      const float inv = 1.0f / psum[rg][reg];
#pragma unroll
      for (int df = 0; df < 4; ++df)
        o[((size_t)(b * 1024 + n)) * 1024 + h * 64 + df * 16 + lo] =
            (bf16)(of[rg][df][reg] * inv);
    }
}

extern "C" void kernel_launch(void* const* d_in, const int* in_sizes, int n_in,
                              void* d_out, int out_size, void* d_ws, size_t ws_size,
                              hipStream_t stream) {
  (void)in_sizes; (void)n_in; (void)out_size; (void)ws_size;
  const float* x = (const float*)d_in[0];
  const float* wqkv = (const float*)d_in[1];
  const float* wproj = (const float*)d_in[2];
  const float* bproj = (const float*)d_in[3];

  char* ws = (char*)d_ws;
  bf16* xb = (bf16*)(ws);                  // 33554432 B (x bf16; reused as attnout)
  bf16* wqb = (bf16*)(ws + 33554432);      // 6291456 B
  bf16* wpb = (bf16*)(ws + 39845888);      // 2097152 B
  float* cosT = (float*)(ws + 41943040);   // 131072 B
  float* sinT = (float*)(ws + 42074112);   // 131072 B
  bf16* qb = (bf16*)(ws + 42205184);       // 33554432 B  (b,h,n,d), pre-scaled
  bf16* kb = (bf16*)(ws + 75759616);       // 33554432 B  (b,h,n,d)
  bf16* vtb = (bf16*)(ws + 109314048);     // 33554432 B  (b,h,d,n)
  // total ws use: 142868480 B

  // all three f32->bf16 conversions in one launch: 5M threads
  f2b_all_kernel<<<20480, 256, 0, stream>>>(x, wqkv, wproj, xb, wqb, wpb);
  table_kernel<<<128, 256, 0, stream>>>(cosT, sinT);

  // QKV: M=16384, N=3072, K=1024 -> 64 bm x 12 bn = 768 blocks of 256x256
  gemm_bt<0, 12><<<768, 512, 0, stream>>>(xb, wqb, qb, kb, vtb, cosT, sinT,
                                          nullptr, nullptr);
  // attention: 1024 blocks (4 q-tiles x 256 heads, XCD-chunked), 8 waves each
  attn_fwd<<<1024, 512, 0, stream>>>(qb, kb, vtb, xb);
  // proj: M=16384, N=1024, K=1024 -> 64 bm x 4 bn = 256 blocks
  gemm_bt<1, 4><<<256, 512, 0, stream>>>(xb, wpb, nullptr, nullptr, nullptr,
                                         nullptr, nullptr, (float*)d_out, bproj);
}

// Round 7
// 253.786 us; speedup vs baseline: 8.3985x; 1.0764x over previous
//
#include <hip/hip_runtime.h>
#include <hip/hip_bf16.h>
#include <math.h>

typedef __bf16 bf16;
typedef bf16 bf16x2 __attribute__((ext_vector_type(2)));
typedef bf16 bf16x4 __attribute__((ext_vector_type(4)));
typedef bf16 bf16x8 __attribute__((ext_vector_type(8)));
typedef float f32x4 __attribute__((ext_vector_type(4)));
typedef float f32x16 __attribute__((ext_vector_type(16)));
typedef unsigned int uint;
typedef uint uint32x4 __attribute__((ext_vector_type(4)));

#define MFMA16(a, b, c) __builtin_amdgcn_mfma_f32_16x16x32_bf16((a), (b), (c), 0, 0, 0)
#define MFMA32(a, b, c) __builtin_amdgcn_mfma_f32_32x32x16_bf16((a), (b), (c), 0, 0, 0)

// q pre-scale: 1/sqrt(64) * log2(e), folded into QKV epilogue so attention
// can use raw v_exp_f32 (exp2) with no per-score multiply.
#define QSCALE 0.18033688011112042f

// async global->LDS, 16B per lane. LDS dest is wave-uniform base + lane*16
// (linear); global src is per-lane (carries the swizzle).
__device__ __forceinline__ void async16(const void* g, void* l) {
  __builtin_amdgcn_global_load_lds(
      (const __attribute__((address_space(1))) void*)g,
      (__attribute__((address_space(3))) void*)l, 16, 0, 0);
}

// pack 2 f32 -> bf16x2 word (compiler fuses to v_cvt_pk_bf16_f32)
__device__ __forceinline__ uint pkbf(float a, float b) {
  bf16x2 t = {(bf16)a, (bf16)b};
  return __builtin_bit_cast(uint, t);
}

// v_permlane32_swap_b32: x' = (lane<32 ? x : y_from_lane-32);
//                        y' = (lane<32 ? x_from_lane+32 : y)
__device__ __forceinline__ void pls(uint& x, uint& y) {
  asm volatile("v_permlane32_swap_b32 %0, %1" : "+v"(x), "+v"(y));
}

// ---------------- fp32 -> bf16 conversion, all three tensors in one launch ----
__global__ __launch_bounds__(256) void f2b_all_kernel(const float* __restrict__ x,
                                                      const float* __restrict__ wqkv,
                                                      const float* __restrict__ wproj,
                                                      bf16* __restrict__ xb,
                                                      bf16* __restrict__ wqb,
                                                      bf16* __restrict__ wpb) {
  int t = blockIdx.x * 256 + threadIdx.x;  // 0 .. 5M-1
  const float* in;
  bf16* out;
  int i;
  if (t < 4194304) {            // x: 16M elems
    in = x; out = xb; i = t * 4;
  } else if (t < 4980736) {     // wqkv: 3M elems
    in = wqkv; out = wqb; i = (t - 4194304) * 4;
  } else {                      // wproj: 1M elems
    in = wproj; out = wpb; i = (t - 4980736) * 4;
  }
  f32x4 v = *(const f32x4*)(in + i);
  bf16x4 o = {(bf16)v[0], (bf16)v[1], (bf16)v[2], (bf16)v[3]};
  *(bf16x4*)(out + i) = o;
}

// ---------------- axial RoPE cos/sin table: [n=1024][d=32] ----------------
__global__ __launch_bounds__(256) void table_kernel(float* __restrict__ cosT,
                                                    float* __restrict__ sinT) {
  int idx = blockIdx.x * 256 + threadIdx.x;
  if (idx >= 1024 * 32) return;
  int n = idx >> 5, d = idx & 31;
  int hf = n >> 5, wf = n & 31;
  int bi = (d & 15) >> 1;
  float base = (1.0f + 73.0f * bi) * 3.14159265358979323846f;  // linspace(1,512,8)[i]*pi
  int p = (d < 16) ? hf : wf;
  float pos = (2.0f * (float)p - 31.0f) * (1.0f / 31.0f);      // linspace(-1,1,32)
  float f = pos * base;
  cosT[idx] = cosf(f);
  sinT[idx] = sinf(f);
}

// ---------------- 256x256 8-wave GEMM, 32-phase counted-vmcnt pipeline ----------
// (verified best — R4/R6: QKV 127.8us, MfmaUtil 34%, VGPR 112, conflicts 0.
//  R3: (512,4) spills acc -> 12x slowdown. R5: 8-phase port regressed at K=1024.)
template <int EPI, int NBN>
__global__ __launch_bounds__(512, 2) void gemm_bt(
    const bf16* __restrict__ A, const bf16* __restrict__ W,
    bf16* __restrict__ oq, bf16* __restrict__ okk, bf16* __restrict__ ovt,
    const float* __restrict__ cosT, const float* __restrict__ sinT,
    float* __restrict__ outF, const float* __restrict__ bias) {
  constexpr int K = 1024;
  __shared__ bf16 As[4][256 * 32];
  __shared__ bf16 Bs[4][256 * 32];

  const int tid = threadIdx.x;
  const int lane = tid & 63;
  const int wid = tid >> 6;          // 0..7
  const int lo = lane & 15, hi = lane >> 4;
  const int wm = wid >> 2;           // 0..1 (M half)
  const int wn = wid & 3;            // 0..3 (N quarter)

  // XCD-stripe block mapping with 4x4 square ordering inside the stripe.
  const int wg = blockIdx.x;
  const int xcd = wg & 7;
  const int i = wg >> 3;             // 0 .. 8*NBN-1
  const int s = i >> 4;              // square index
  const int r = i & 15;
  const int bm = xcd * 8 + (s & 1) * 4 + (r & 3);
  const int bn = (s >> 1) * 4 + (r >> 2);

  const bf16* Ab = A + (size_t)bm * 256 * K;
  const bf16* Wb = W + (size_t)bn * 256 * K;

  const f32x4 fzero = {0.f, 0.f, 0.f, 0.f};
  f32x4 acc[8][4];
#pragma unroll
  for (int i2 = 0; i2 < 8; ++i2)
#pragma unroll
    for (int j = 0; j < 4; ++j) acc[i2][j] = fzero;

  size_t srcOff[2];
  int ldsOff[2];
#pragma unroll
  for (int i2 = 0; i2 < 2; ++i2) {
    const int c = i2 * 512 + tid;
    const int row = c >> 2, g = c & 3;
    const int gsrc = g ^ ((row >> 1) & 3);
    srcOff[i2] = (size_t)row * K + gsrc * 8;
    ldsOff[i2] = c * 8;
  }

  auto stageSlot = [&](int slot, int kh) {
#pragma unroll
    for (int i2 = 0; i2 < 2; ++i2)
      async16(Ab + srcOff[i2] + kh * 32, &As[slot][ldsOff[i2]]);
#pragma unroll
    for (int i2 = 0; i2 < 2; ++i2)
      async16(Wb + srcOff[i2] + kh * 32, &Bs[slot][ldsOff[i2]]);
  };

  auto compute = [&](int slot) {
    bf16x8 af[8], bf[4];
#pragma unroll
    for (int mf = 0; mf < 8; ++mf) {
      const int row = wm * 128 + mf * 16 + lo;
      const int g = hi ^ ((row >> 1) & 3);
      af[mf] = *(const bf16x8*)&As[slot][row * 32 + g * 8];
    }
#pragma unroll
    for (int nf = 0; nf < 4; ++nf) {
      const int row = wn * 64 + nf * 16 + lo;
      const int g = hi ^ ((row >> 1) & 3);
      bf[nf] = *(const bf16x8*)&Bs[slot][row * 32 + g * 8];
    }
    __builtin_amdgcn_s_setprio(1);
#pragma unroll
    for (int mf = 0; mf < 8; ++mf)
#pragma unroll
      for (int nf = 0; nf < 4; ++nf)
        acc[mf][nf] = MFMA16(af[mf], bf[nf], acc[mf][nf]);
    __builtin_amdgcn_s_setprio(0);
  };

  stageSlot(0, 0);
  stageSlot(1, 1);

  for (int kt = 0; kt < 7; ++kt) {
#pragma unroll
    for (int ph = 0; ph < 4; ++ph) {
      stageSlot((ph + 2) & 3, kt * 4 + ph + 2);
      asm volatile("s_waitcnt vmcnt(8)" ::: "memory");
      __builtin_amdgcn_s_barrier();
      compute(ph);
    }
  }
  stageSlot(2, 30);
  asm volatile("s_waitcnt vmcnt(8)" ::: "memory");
  __builtin_amdgcn_s_barrier();
  compute(0);
  stageSlot(3, 31);
  asm volatile("s_waitcnt vmcnt(8)" ::: "memory");
  __builtin_amdgcn_s_barrier();
  compute(1);
  asm volatile("s_waitcnt vmcnt(4)" ::: "memory");
  __builtin_amdgcn_s_barrier();
  compute(2);
  asm volatile("s_waitcnt vmcnt(0)" ::: "memory");
  __builtin_amdgcn_s_barrier();
  compute(3);

  const int rb0 = bm * 256 + wm * 128;
  const int jb0 = bn * 256 + wn * 64;

  if constexpr (EPI == 0) {
#pragma unroll
    for (int ac = 0; ac < 4; ++ac) {
      const int j = jb0 + ac * 16 + lo;
      const int which = j >> 10;        // 0=q 1=k 2=v (uniform per wave)
      const int f = j & 1023;
      const int h = f >> 6, d = f & 63; // d = ac*16+lo; d<32 <=> ac<2
#pragma unroll
      for (int ar = 0; ar < 8; ++ar) {
        const int rb = rb0 + ar * 16 + 4 * hi;
        f32x4 v = acc[ar][ac];
        if (which == 2) {
          const int b = rb >> 10, n0 = rb & 1023;
          bf16x4 pk = {(bf16)v[0], (bf16)v[1], (bf16)v[2], (bf16)v[3]};
          *(bf16x4*)(ovt + ((size_t)((b * 16 + h) * 64 + d)) * 1024 + n0) = pk;
        } else {
          bf16* dst = which ? okk : oq;
          const float sc = which ? 1.0f : QSCALE;
#pragma unroll
          for (int reg = 0; reg < 4; ++reg) {
            const int r2 = rb + reg;
            const int b = r2 >> 10, n = r2 & 1023;
            float val = v[reg];
            float res;
            if (d < 32) {
              float c = cosT[n * 32 + d];
              float sn = sinT[n * 32 + d];
              float pp = __shfl_xor(val, 1);  // rotary partner: adjacent lane = d^1
              res = (d & 1) ? fmaf(val, c, pp * sn) : fmaf(val, c, -(pp * sn));
            } else {
              res = val;
            }
            dst[((size_t)((b * 16 + h) * 1024 + n)) * 64 + d] = (bf16)(res * sc);
          }
        }
      }
    }
  } else {
#pragma unroll
    for (int ac = 0; ac < 4; ++ac) {
      const int j = jb0 + ac * 16 + lo;
      const float bv = bias[j];
#pragma unroll
      for (int ar = 0; ar < 8; ++ar) {
        const int rb = rb0 + ar * 16 + 4 * hi;
#pragma unroll
        for (int reg = 0; reg < 4; ++reg)
          outF[(size_t)(rb + reg) * 1024 + j] = acc[ar][ac][reg] + bv;
      }
    }
  }
}

// ---------------- flash attention v3: 32x32 MFMA, swapped QK^T, P in registers --
// 8 waves x 32 q-rows (256 rows/block). K/V tiles [64][64] LINEAR, staged via
// global_load_lds with XOR swizzle (group g at row r holds global g^(r&7);
// same XOR on read), double-buffered, counted vmcnt(2).
// SWAPPED QK^T: z[B] = mfma32(K-block-B, Q) -> S^T: q = lane&31 (lane-local
// P rows!), key = (reg&3)+8(reg>>2)+4*(lane>>5) + 32B. P = exp2(S) stays in
// registers; psum is a per-lane scalar (q = lane&31), reduced once at the end
// via shfl_xor(32). NO Pt LDS round-trip (old version: 32 ds_write_b16 +
// 4 ds_read_b128 per wave-iter -> ~40% of the LDS-port time, eliminated).
// P -> PV A-frag regroup (k = 8*(l>>5)+j vs held 4-row C/D groups): 16 bf16x2
// packs + 8 v_permlane32_swap per iter: a_pv[kb] words {w0,w1,w2,w3} where
// (w0,w2) = pls(c[B][4b], c[B][4b+2]), (w1,w3) = pls(c[B][4b+1], c[B][4b+3]),
// b=kb&1, B=kb>>1 (derived from the verified 32x32 A/C-D layouts; one swap
// fills two output words).
// PV: of[db] += mfma32(a_pv[kb], V^T-frag); V^T tile rows d, cols key: B-frag
// (col=d=l&31, k=key=8s+j) reads Vt[32db+l31][16kb+8s..] — clean b128s.
// Final: inv = 1/psum bounced via tiny Psm[8][32] LDS (C/D q-rows differ from
// lane-local q). Output (b, n, h*64+d) bf16 — same as before.
__global__ __launch_bounds__(512, 4) void attn_fwd(const bf16* __restrict__ q,
                                                   const bf16* __restrict__ k,
                                                   const bf16* __restrict__ vt,
                                                   bf16* __restrict__ o) {
  __shared__ bf16 Kt[2][64 * 64];
  __shared__ bf16 Vt[2][64 * 64];
  __shared__ float Psm[8][32];
  const int tid = threadIdx.x;
  const int lane = tid & 63, wid = tid >> 6;
  const int l31 = lane & 31;
  const int s = lane >> 5;          // half-wave index
  const int m7 = l31 & 7;
  // XCD-aware mapping: all 4 q-tiles of head bh land on XCD (bh&7)
  const int j = blockIdx.x;                  // 0..1023
  const int bh = (j & 7) + ((j >> 5) << 3);  // 0..255
  const int qt = (j >> 3) & 3;               // 0..3
  const bf16* qg = q + (size_t)bh * 65536;
  const bf16* kg = k + (size_t)bh * 65536;
  const bf16* vg = vt + (size_t)bh * 65536;

  // Q as B-frags: qf[kb4] elem j = Q[qrow][16*kb4 + 8*s + j]
  const int qrow = qt * 256 + wid * 32 + l31;
  bf16x8 qf[4];
#pragma unroll
  for (int kb4 = 0; kb4 < 4; ++kb4)
    qf[kb4] = *(const bf16x8*)(qg + (size_t)qrow * 64 + kb4 * 16 + s * 8);

  const int srow = tid >> 3;
  const int sgsrc = (tid & 7) ^ (srow & 7);
  auto stageKV = [&](int buf, int kv) {
    async16(kg + (size_t)(kv * 64 + srow) * 64 + sgsrc * 8, &Kt[buf][tid * 8]);
    async16(vg + (size_t)srow * 1024 + kv * 64 + sgsrc * 8, &Vt[buf][tid * 8]);
  };

  // drain qf loads so the async vmcnt bookkeeping below is exact
  asm volatile("s_waitcnt vmcnt(0)" ::: "memory");
  stageKV(0, 0);

  f32x16 of0 = {0.f, 0.f, 0.f, 0.f, 0.f, 0.f, 0.f, 0.f,
                0.f, 0.f, 0.f, 0.f, 0.f, 0.f, 0.f, 0.f};
  f32x16 of1 = of0;
  float psum = 0.f;

  for (int kv = 0; kv < 16; ++kv) {
    const int cur = kv & 1;
    if (kv < 15) {
      stageKV(cur ^ 1, kv + 1);
      asm volatile("s_waitcnt vmcnt(2)" ::: "memory");
    } else {
      asm volatile("s_waitcnt vmcnt(0)" ::: "memory");
    }
    __builtin_amdgcn_s_barrier();

    // S^T = K Q (swapped): z0 = keys 0..31, z1 = keys 32..63 (this tile)
    f32x16 z0 = {0.f, 0.f, 0.f, 0.f, 0.f, 0.f, 0.f, 0.f,
                 0.f, 0.f, 0.f, 0.f, 0.f, 0.f, 0.f, 0.f};
    f32x16 z1 = z0;
#pragma unroll
    for (int kb4 = 0; kb4 < 4; ++kb4) {
      bf16x8 k0 = *(const bf16x8*)&Kt[cur][l31 * 64 + (((2 * kb4 + s) ^ m7) * 8)];
      bf16x8 k1 = *(const bf16x8*)&Kt[cur][(32 + l31) * 64 + (((2 * kb4 + s) ^ m7) * 8)];
      z0 = MFMA32(k0, qf[kb4], z0);
      z1 = MFMA32(k1, qf[kb4], z1);
    }

    // P = exp2(S^T) in-register; pack pairs (regs 2m,2m+1 = consecutive keys)
    uint c0[8], c1[8];
#pragma unroll
    for (int m = 0; m < 8; ++m) {
      float a0 = __builtin_amdgcn_exp2f(z0[2 * m]);
      float b0 = __builtin_amdgcn_exp2f(z0[2 * m + 1]);
      float a1 = __builtin_amdgcn_exp2f(z1[2 * m]);
      float b1 = __builtin_amdgcn_exp2f(z1[2 * m + 1]);
      psum += (a0 + b0) + (a1 + b1);
      c0[m] = pkbf(a0, b0);
      c1[m] = pkbf(a1, b1);
    }

    // O += P V: per 16-key block kb, regroup P into A-frag via 2 permlane swaps
    auto pv = [&](uint* cc, int bb, int kb) {
      uint w0 = cc[4 * bb], w2 = cc[4 * bb + 2];
      uint w1 = cc[4 * bb + 1], w3 = cc[4 * bb + 3];
      pls(w0, w2);
      pls(w1, w3);
      uint32x4 W = {w0, w1, w2, w3};
      bf16x8 apv = __builtin_bit_cast(bf16x8, W);
      bf16x8 vb0 = *(const bf16x8*)&Vt[cur][l31 * 64 + (((2 * kb + s) ^ m7) * 8)];
      bf16x8 vb1 = *(const bf16x8*)&Vt[cur][(32 + l31) * 64 + (((2 * kb + s) ^ m7) * 8)];
      of0 = MFMA32(apv, vb0, of0);
      of1 = MFMA32(apv, vb1, of1);
    };
    pv(c0, 0, 0);
    pv(c0, 1, 1);
    pv(c1, 0, 2);
    pv(c1, 1, 3);

    __syncthreads();  // all waves done reading cur before next stage overwrites
  }

  // psum: lane l and l+32 hold partials for the same q = l&31
  psum += __shfl_xor(psum, 32);
  const float inv = 1.0f / psum;
  if (lane < 32) Psm[wid][l31] = inv;
  __syncthreads();

  // write attnout as (b, n, h*64+d) bf16; C/D row r -> q = (r&3)+8*(r>>2)+4*s
  const int b = bh >> 4, h = bh & 15;
#pragma unroll
  for (int r = 0; r < 16; ++r) {
    const int qr = (r & 3) + 8 * (r >> 2) + 4 * s;
    const float iv = Psm[wid][qr];
    const int n = qt * 256 + wid * 32 + qr;
    const size_t base = ((size_t)(b * 1024 + n)) * 1024 + h * 64 + l31;
    o[base] = (bf16)(of0[r] * iv);
    o[base + 32] = (bf16)(of1[r] * iv);
  }
}

extern "C" void kernel_launch(void* const* d_in, const int* in_sizes, int n_in,
                              void* d_out, int out_size, void* d_ws, size_t ws_size,
                              hipStream_t stream) {
  (void)in_sizes; (void)n_in; (void)out_size; (void)ws_size;
  const float* x = (const float*)d_in[0];
  const float* wqkv = (const float*)d_in[1];
  const float* wproj = (const float*)d_in[2];
  const float* bproj = (const float*)d_in[3];

  char* ws = (char*)d_ws;
  bf16* xb = (bf16*)(ws);                  // 33554432 B (x bf16; reused as attnout)
  bf16* wqb = (bf16*)(ws + 33554432);      // 6291456 B
  bf16* wpb = (bf16*)(ws + 39845888);      // 2097152 B
  float* cosT = (float*)(ws + 41943040);   // 131072 B
  float* sinT = (float*)(ws + 42074112);   // 131072 B
  bf16* qb = (bf16*)(ws + 42205184);       // 33554432 B  (b,h,n,d), pre-scaled
  bf16* kb = (bf16*)(ws + 75759616);       // 33554432 B  (b,h,n,d)
  bf16* vtb = (bf16*)(ws + 109314048);     // 33554432 B  (b,h,d,n)
  // total ws use: 142868480 B

  // all three f32->bf16 conversions in one launch: 5M threads
  f2b_all_kernel<<<20480, 256, 0, stream>>>(x, wqkv, wproj, xb, wqb, wpb);
  table_kernel<<<128, 256, 0, stream>>>(cosT, sinT);

  // QKV: M=16384, N=3072, K=1024 -> 64 bm x 12 bn = 768 blocks of 256x256
  gemm_bt<0, 12><<<768, 512, 0, stream>>>(xb, wqb, qb, kb, vtb, cosT, sinT,
                                          nullptr, nullptr);
  // attention: 1024 blocks (4 q-tiles x 256 heads, XCD-chunked), 8 waves each
  attn_fwd<<<1024, 512, 0, stream>>>(qb, kb, vtb, xb);
  // proj: M=16384, N=1024, K=1024 -> 64 bm x 4 bn = 256 blocks
  gemm_bt<1, 4><<<256, 512, 0, stream>>>(xb, wpb, nullptr, nullptr, nullptr,
                                         nullptr, nullptr, (float*)d_out, bproj);
}